// Round 4
// baseline (487.050 us; speedup 1.0000x reference)
//
#include <hip/hip_runtime.h>
#include <hip/hip_fp16.h>
#include <cstdint>
#include <cstddef>

#define NPB_SHIFT 8                      // 256 dst-nodes per bucket
#define NPB (1 << NPB_SHIFT)
#define CHUNK 2048                       // edges per partition block

// ---------------- graph preprocessing ----------------

__global__ void k_zero_i32(int* __restrict__ p, int n) {
  int i = blockIdx.x * blockDim.x + threadIdx.x;
  if (i < n) p[i] = 0;
}

__global__ void k_count(const int* __restrict__ dst, int* __restrict__ count, int E) {
  int e = blockIdx.x * blockDim.x + threadIdx.x;
  if (e < E) atomicAdd(&count[dst[e]], 1);
}

__global__ void k_dinv(const int* __restrict__ count, float* __restrict__ dinv, int n) {
  int i = blockIdx.x * blockDim.x + threadIdx.x;
  if (i < n) dinv[i] = rsqrtf((float)(count[i] + 1));  // +1 self-loop
}

// inclusive scan of 1024-chunks
__global__ void k_scan1(const int* __restrict__ count, int* __restrict__ incl,
                        int* __restrict__ bsum, int n) {
  __shared__ int tmp[1024];
  int tid = threadIdx.x;
  int gid = blockIdx.x * 1024 + tid;
  int v = (gid < n) ? count[gid] : 0;
  tmp[tid] = v;
  __syncthreads();
  for (int off = 1; off < 1024; off <<= 1) {
    int t = (tid >= off) ? tmp[tid - off] : 0;
    __syncthreads();
    tmp[tid] += t;
    __syncthreads();
  }
  if (gid < n) incl[gid] = tmp[tid];
  if (tid == 1023) bsum[blockIdx.x] = tmp[tid];
}

__global__ void k_scan2(int* __restrict__ bsum, int nb) {
  __shared__ int tmp[1024];
  int tid = threadIdx.x;
  int v = (tid < nb) ? bsum[tid] : 0;
  tmp[tid] = v;
  __syncthreads();
  for (int off = 1; off < 1024; off <<= 1) {
    int t = (tid >= off) ? tmp[tid - off] : 0;
    __syncthreads();
    tmp[tid] += t;
    __syncthreads();
  }
  if (tid < nb) bsum[tid] = tmp[tid] - v;  // exclusive
}

__global__ void k_scan3(const int* __restrict__ count, int* __restrict__ offset,
                        const int* __restrict__ bsum, int n, int E) {
  int gid = blockIdx.x * blockDim.x + threadIdx.x;
  if (gid < n) offset[gid] = offset[gid] - count[gid] + bsum[gid >> 10];
  if (gid == 0) offset[n] = E;
}

// bucket fill counters start at each bucket's CSR base
__global__ void k_bfill(const int* __restrict__ offset, int* __restrict__ bfill, int nbuck) {
  int b = blockIdx.x * blockDim.x + threadIdx.x;
  if (b < nbuck) bfill[b] = offset[b << NPB_SHIFT];
}

// pass 1: LDS multisplit into coarse dst-buckets; packed (src<<8)|dst_local, 4B/edge
__global__ __launch_bounds__(256) void k_partition(const int* __restrict__ src,
                                                   const int* __restrict__ dst,
                                                   int* __restrict__ bfill,
                                                   unsigned* __restrict__ tmp,
                                                   int E, int nbuck) {
  __shared__ int cnt[512];
  __shared__ int base[512];
  __shared__ int cur[512];
  int tid = threadIdx.x;
  int cbase = blockIdx.x * CHUNK;
  for (int i = tid; i < nbuck; i += 256) { cnt[i] = 0; cur[i] = 0; }
  __syncthreads();
  int s[8], d[8];
  bool valid[8];
#pragma unroll
  for (int u = 0; u < 8; ++u) {
    int e = cbase + u * 256 + tid;
    valid[u] = e < E;
    s[u] = valid[u] ? src[e] : 0;
    d[u] = valid[u] ? dst[e] : 0;
    if (valid[u]) atomicAdd(&cnt[d[u] >> NPB_SHIFT], 1);
  }
  __syncthreads();
  for (int i = tid; i < nbuck; i += 256)
    if (cnt[i]) base[i] = atomicAdd(&bfill[i], cnt[i]);
  __syncthreads();
#pragma unroll
  for (int u = 0; u < 8; ++u) {
    if (valid[u]) {
      int b = d[u] >> NPB_SHIFT;
      int r = atomicAdd(&cur[b], 1);
      tmp[base[b] + r] = ((unsigned)s[u] << NPB_SHIFT) | (unsigned)(d[u] & (NPB - 1));
    }
  }
}

// pass 2: one block per bucket; LDS fill counters -> exact CSR, writes L2-local
__global__ __launch_bounds__(256) void k_csr(const unsigned* __restrict__ tmp,
                                             const int* __restrict__ offset,
                                             const float* __restrict__ dinv,
                                             int2* __restrict__ sedge, int N) {
  __shared__ int fillL[NPB];
  __shared__ float dloc[NPB];
  int b = blockIdx.x;
  int nbase = b << NPB_SHIFT;
  int nend = min(nbase + NPB, N);
  int nloc = nend - nbase;
  int tid = threadIdx.x;
  for (int i = tid; i < nloc; i += 256) {
    fillL[i] = offset[nbase + i];
    dloc[i] = dinv[nbase + i];
  }
  __syncthreads();
  int ebeg = offset[nbase];
  int eend = offset[nend];
  int j = ebeg + tid;
  for (; j + 3 * 256 < eend; j += 4 * 256) {
    unsigned p[4];
#pragma unroll
    for (int u = 0; u < 4; ++u) p[u] = tmp[j + u * 256];
    float dv[4];
#pragma unroll
    for (int u = 0; u < 4; ++u) dv[u] = dinv[p[u] >> NPB_SHIFT];
#pragma unroll
    for (int u = 0; u < 4; ++u) {
      int dl = p[u] & (NPB - 1);
      int pos = atomicAdd(&fillL[dl], 1);
      sedge[pos] = make_int2((int)(p[u] >> NPB_SHIFT), __float_as_int(dv[u] * dloc[dl]));
    }
  }
  for (; j < eend; j += 256) {
    unsigned p = tmp[j];
    int dl = p & (NPB - 1);
    int s = (int)(p >> NPB_SHIFT);
    int pos = atomicAdd(&fillL[dl], 1);
    sedge[pos] = make_int2(s, __float_as_int(dinv[s] * dloc[dl]));
  }
}

// ---------------- dense layers ----------------
// One wave per node; W column `lane` in VGPRs; x row wave-uniform scalar loads.
// HALF_OUT: store result as fp16 (feeds the gather kernels).
template <int K, int COLS, bool HALF_OUT>
__global__ __launch_bounds__(256) void k_gemm(const float* __restrict__ x,
                                              const float* __restrict__ W,
                                              void* __restrict__ outp, int n) {
  int lane = threadIdx.x & 63;
  int gw = (blockIdx.x * blockDim.x + threadIdx.x) >> 6;
  int nw = (gridDim.x * blockDim.x) >> 6;
  float wreg[K];
#pragma unroll
  for (int k = 0; k < K; ++k) wreg[k] = 0.f;
  if (lane < COLS) {
#pragma unroll
    for (int k = 0; k < K; ++k) wreg[k] = W[k * COLS + lane];
  }
  for (int node = gw; node < n; node += nw) {
    int un = __builtin_amdgcn_readfirstlane(node);
    const float* xr = x + (size_t)un * K;
    float acc = 0.f;
#pragma unroll
    for (int k = 0; k < K; ++k) acc = fmaf(xr[k], wreg[k], acc);
    if (lane < COLS) {
      if (HALF_OUT)
        ((__half*)outp)[(size_t)un * COLS + lane] = __float2half(acc);
      else
        ((float*)outp)[(size_t)un * COLS + lane] = acc;
    }
  }
}

// ---------------- aggregation (CSR gather of fp16 features, fp32 accum) ----------
template <int F, bool RELU, bool HALF_OUT>
__global__ __launch_bounds__(256) void k_agg(const __half* __restrict__ h,
                                             const int* __restrict__ offset,
                                             const int2* __restrict__ sedge,
                                             const float* __restrict__ dinv,
                                             const float* __restrict__ bias,
                                             void* __restrict__ outp, int n) {
  int lane = threadIdx.x & 63;
  int node = (blockIdx.x * blockDim.x + threadIdx.x) >> 6;
  if (node >= n) return;
  float di = dinv[node];
  float acc = 0.f;
  if (lane < F) acc = __half2float(h[(size_t)node * F + lane]) * di * di;  // self loop
  int beg = offset[node], end = offset[node + 1];
  int j = beg;
  for (; j + 8 <= end; j += 8) {
    int2 e[8];
#pragma unroll
    for (int u = 0; u < 8; ++u) e[u] = sedge[j + u];
    __half v[8];
#pragma unroll
    for (int u = 0; u < 8; ++u)
      v[u] = (lane < F) ? h[(size_t)e[u].x * F + lane] : __half(0.f);
#pragma unroll
    for (int u = 0; u < 8; ++u) acc = fmaf(__half2float(v[u]), __int_as_float(e[u].y), acc);
  }
  for (; j + 4 <= end; j += 4) {
    int2 e[4];
#pragma unroll
    for (int u = 0; u < 4; ++u) e[u] = sedge[j + u];
    __half v[4];
#pragma unroll
    for (int u = 0; u < 4; ++u)
      v[u] = (lane < F) ? h[(size_t)e[u].x * F + lane] : __half(0.f);
#pragma unroll
    for (int u = 0; u < 4; ++u) acc = fmaf(__half2float(v[u]), __int_as_float(e[u].y), acc);
  }
  for (; j < end; ++j) {
    int2 e = sedge[j];
    if (lane < F) acc = fmaf(__half2float(h[(size_t)e.x * F + lane]), __int_as_float(e.y), acc);
  }
  if (lane < F) {
    float vv = acc + bias[lane];
    if (RELU) vv = fmaxf(vv, 0.f);
    if (HALF_OUT)
      ((__half*)outp)[(size_t)node * F + lane] = __float2half(vv);
    else
      ((float*)outp)[(size_t)node * F + lane] = vv;
  }
}

// ---------------- launch ----------------

extern "C" void kernel_launch(void* const* d_in, const int* in_sizes, int n_in,
                              void* d_out, int out_size, void* d_ws, size_t ws_size,
                              hipStream_t stream) {
  const float* x  = (const float*)d_in[0];
  const int*   ei = (const int*)d_in[1];
  const float* W1 = (const float*)d_in[2];
  const float* b1 = (const float*)d_in[3];
  const float* W2 = (const float*)d_in[4];
  const float* b2 = (const float*)d_in[5];
  float* out = (float*)d_out;

  const int F_IN = 128, HID = 64, C = 40;
  int N = in_sizes[0] / F_IN;
  int E = in_sizes[1] / 2;
  const int* src = ei;
  const int* dst = ei + E;
  int nbuck = (N + NPB - 1) >> NPB_SHIFT;   // 391 for N=100000

  char* w = (char*)d_ws;
  size_t o = 0;
  auto alloc = [&](size_t bytes) -> void* {
    void* p = w + o;
    o = (o + bytes + 255) & ~(size_t)255;
    return p;
  };
  float*    dinv   = (float*)alloc((size_t)N * 4);
  int*      count  = (int*)alloc((size_t)N * 4);
  int*      offset = (int*)alloc((size_t)(N + 1) * 4);
  int*      bsum   = (int*)alloc(1024 * 4);
  int*      bfill  = (int*)alloc((size_t)nbuck * 4);
  unsigned* tmp    = (unsigned*)alloc((size_t)E * 4);
  int2*     sedge  = (int2*)alloc((size_t)E * 8);
  __half*   h      = (__half*)alloc((size_t)N * HID * 2);   // fp16 gather source
  float*    h1     = (float*)alloc((size_t)N * HID * 4);    // fp32, streamed by gemm2
  __half*   h2     = (__half*)alloc((size_t)N * C * 2);     // fp16 gather source

  int nb = (N + 1023) / 1024;

  dim3 b256(256);
  dim3 gN((N + 255) / 256), gE((E + 255) / 256);

  // degree / offsets
  k_zero_i32<<<gN, b256, 0, stream>>>(count, N);
  k_count<<<gE, b256, 0, stream>>>(dst, count, E);
  k_dinv<<<gN, b256, 0, stream>>>(count, dinv, N);
  k_scan1<<<dim3(nb), dim3(1024), 0, stream>>>(count, offset, bsum, N);
  k_scan2<<<dim3(1), dim3(1024), 0, stream>>>(bsum, nb);
  k_scan3<<<gN, b256, 0, stream>>>(count, offset, bsum, N, E);

  // locality-aware CSR build
  k_bfill<<<dim3((nbuck + 255) / 256), b256, 0, stream>>>(offset, bfill, nbuck);
  k_partition<<<dim3((E + CHUNK - 1) / CHUNK), b256, 0, stream>>>(src, dst, bfill, tmp, E, nbuck);
  k_csr<<<dim3(nbuck), b256, 0, stream>>>(tmp, offset, dinv, sedge, N);

  // layer 1
  k_gemm<128, 64, true><<<dim3(768), b256, 0, stream>>>(x, W1, h, N);
  k_agg<64, true, false><<<dim3((N + 3) / 4), b256, 0, stream>>>(h, offset, sedge, dinv, b1, h1, N);

  // layer 2
  k_gemm<64, 40, true><<<dim3(768), b256, 0, stream>>>(h1, W2, h2, N);
  k_agg<40, false, false><<<dim3((N + 3) / 4), b256, 0, stream>>>(h2, offset, sedge, dinv, b2, out, N);
}

// Round 5
// 435.086 us; speedup vs baseline: 1.1194x; 1.1194x over previous
//
#include <hip/hip_runtime.h>
#include <hip/hip_fp16.h>
#include <cstdint>
#include <cstddef>

#define NPB_SHIFT 8                      // 256 dst-nodes per bucket
#define NPB (1 << NPB_SHIFT)
#define CHUNK 2048                       // edges per partition block

__device__ inline float ush2f(unsigned short u) {
  __half_raw r; r.x = u;
  return __half2float(__half(r));
}
__device__ inline float4 h4f(ushort4 v) {
  return make_float4(ush2f(v.x), ush2f(v.y), ush2f(v.z), ush2f(v.w));
}

// ---------------- graph preprocessing ----------------

__global__ void k_zero_i32(int* __restrict__ p, int n) {
  int i = blockIdx.x * blockDim.x + threadIdx.x;
  if (i < n) p[i] = 0;
}

__global__ void k_count(const int* __restrict__ dst, int* __restrict__ count, int E) {
  int e = blockIdx.x * blockDim.x + threadIdx.x;
  if (e < E) atomicAdd(&count[dst[e]], 1);
}

__global__ void k_dinv(const int* __restrict__ count, float* __restrict__ dinv, int n) {
  int i = blockIdx.x * blockDim.x + threadIdx.x;
  if (i < n) dinv[i] = rsqrtf((float)(count[i] + 1));  // +1 self-loop
}

// inclusive scan of 1024-chunks
__global__ void k_scan1(const int* __restrict__ count, int* __restrict__ incl,
                        int* __restrict__ bsum, int n) {
  __shared__ int tmp[1024];
  int tid = threadIdx.x;
  int gid = blockIdx.x * 1024 + tid;
  int v = (gid < n) ? count[gid] : 0;
  tmp[tid] = v;
  __syncthreads();
  for (int off = 1; off < 1024; off <<= 1) {
    int t = (tid >= off) ? tmp[tid - off] : 0;
    __syncthreads();
    tmp[tid] += t;
    __syncthreads();
  }
  if (gid < n) incl[gid] = tmp[tid];
  if (tid == 1023) bsum[blockIdx.x] = tmp[tid];
}

__global__ void k_scan2(int* __restrict__ bsum, int nb) {
  __shared__ int tmp[1024];
  int tid = threadIdx.x;
  int v = (tid < nb) ? bsum[tid] : 0;
  tmp[tid] = v;
  __syncthreads();
  for (int off = 1; off < 1024; off <<= 1) {
    int t = (tid >= off) ? tmp[tid - off] : 0;
    __syncthreads();
    tmp[tid] += t;
    __syncthreads();
  }
  if (tid < nb) bsum[tid] = tmp[tid] - v;  // exclusive
}

__global__ void k_scan3(const int* __restrict__ count, int* __restrict__ offset,
                        const int* __restrict__ bsum, int n, int E) {
  int gid = blockIdx.x * blockDim.x + threadIdx.x;
  if (gid < n) offset[gid] = offset[gid] - count[gid] + bsum[gid >> 10];
  if (gid == 0) offset[n] = E;
}

__global__ void k_bfill(const int* __restrict__ offset, int* __restrict__ bfill, int nbuck) {
  int b = blockIdx.x * blockDim.x + threadIdx.x;
  if (b < nbuck) bfill[b] = offset[b << NPB_SHIFT];
}

// pass 1: LDS multisplit into coarse dst-buckets; packed (src<<8)|dst_local, 4B/edge
__global__ __launch_bounds__(256) void k_partition(const int* __restrict__ src,
                                                   const int* __restrict__ dst,
                                                   int* __restrict__ bfill,
                                                   unsigned* __restrict__ tmp,
                                                   int E, int nbuck) {
  __shared__ int cnt[512];
  __shared__ int base[512];
  __shared__ int cur[512];
  int tid = threadIdx.x;
  int cbase = blockIdx.x * CHUNK;
  for (int i = tid; i < nbuck; i += 256) { cnt[i] = 0; cur[i] = 0; }
  __syncthreads();
  int s[8], d[8];
  bool valid[8];
#pragma unroll
  for (int u = 0; u < 8; ++u) {
    int e = cbase + u * 256 + tid;
    valid[u] = e < E;
    s[u] = valid[u] ? src[e] : 0;
    d[u] = valid[u] ? dst[e] : 0;
    if (valid[u]) atomicAdd(&cnt[d[u] >> NPB_SHIFT], 1);
  }
  __syncthreads();
  for (int i = tid; i < nbuck; i += 256)
    if (cnt[i]) base[i] = atomicAdd(&bfill[i], cnt[i]);
  __syncthreads();
#pragma unroll
  for (int u = 0; u < 8; ++u) {
    if (valid[u]) {
      int b = d[u] >> NPB_SHIFT;
      int r = atomicAdd(&cur[b], 1);
      tmp[base[b] + r] = ((unsigned)s[u] << NPB_SHIFT) | (unsigned)(d[u] & (NPB - 1));
    }
  }
}

// pass 2: one block per bucket; LDS fill counters -> exact CSR, writes L2-local
__global__ __launch_bounds__(256) void k_csr(const unsigned* __restrict__ tmp,
                                             const int* __restrict__ offset,
                                             const float* __restrict__ dinv,
                                             int2* __restrict__ sedge, int N) {
  __shared__ int fillL[NPB];
  __shared__ float dloc[NPB];
  int b = blockIdx.x;
  int nbase = b << NPB_SHIFT;
  int nend = min(nbase + NPB, N);
  int nloc = nend - nbase;
  int tid = threadIdx.x;
  for (int i = tid; i < nloc; i += 256) {
    fillL[i] = offset[nbase + i];
    dloc[i] = dinv[nbase + i];
  }
  __syncthreads();
  int ebeg = offset[nbase];
  int eend = offset[nend];
  int j = ebeg + tid;
  for (; j + 3 * 256 < eend; j += 4 * 256) {
    unsigned p[4];
#pragma unroll
    for (int u = 0; u < 4; ++u) p[u] = tmp[j + u * 256];
    float dv[4];
#pragma unroll
    for (int u = 0; u < 4; ++u) dv[u] = dinv[p[u] >> NPB_SHIFT];
#pragma unroll
    for (int u = 0; u < 4; ++u) {
      int dl = p[u] & (NPB - 1);
      int pos = atomicAdd(&fillL[dl], 1);
      sedge[pos] = make_int2((int)(p[u] >> NPB_SHIFT), __float_as_int(dv[u] * dloc[dl]));
    }
  }
  for (; j < eend; j += 256) {
    unsigned p = tmp[j];
    int dl = p & (NPB - 1);
    int s = (int)(p >> NPB_SHIFT);
    int pos = atomicAdd(&fillL[dl], 1);
    sedge[pos] = make_int2(s, __float_as_int(dinv[s] * dloc[dl]));
  }
}

// ---------------- dense layers ----------------
template <int K, int COLS, bool HALF_OUT>
__global__ __launch_bounds__(256) void k_gemm(const float* __restrict__ x,
                                              const float* __restrict__ W,
                                              void* __restrict__ outp, int n) {
  int lane = threadIdx.x & 63;
  int gw = (blockIdx.x * blockDim.x + threadIdx.x) >> 6;
  int nw = (gridDim.x * blockDim.x) >> 6;
  float wreg[K];
#pragma unroll
  for (int k = 0; k < K; ++k) wreg[k] = 0.f;
  if (lane < COLS) {
#pragma unroll
    for (int k = 0; k < K; ++k) wreg[k] = W[k * COLS + lane];
  }
  for (int node = gw; node < n; node += nw) {
    int un = __builtin_amdgcn_readfirstlane(node);
    const float* xr = x + (size_t)un * K;
    float acc = 0.f;
#pragma unroll
    for (int k = 0; k < K; ++k) acc = fmaf(xr[k], wreg[k], acc);
    if (lane < COLS) {
      if (HALF_OUT)
        ((__half*)outp)[(size_t)un * COLS + lane] = __float2half(acc);
      else
        ((float*)outp)[(size_t)un * COLS + lane] = acc;
    }
  }
}

// ---------------- aggregation: 4 edges per wave-request ----------------
// Wave = 4 groups x 16 lanes. Group g handles edge j+g; lane t of a group
// loads ushort4 = 4 fp16 feats. One gather instruction covers 4 edges.
// Cross-group reduce via shfl_xor(16,32); lanes 0..F/4-1 store float4.
template <int F, bool RELU>
__global__ __launch_bounds__(256) void k_agg_v(const ushort4* __restrict__ h4,
                                               const int* __restrict__ offset,
                                               const int2* __restrict__ sedge,
                                               const float* __restrict__ dinv,
                                               const float4* __restrict__ bias4,
                                               float4* __restrict__ out4, int n) {
  constexpr int F4 = F / 4;            // ushort4 per row (16 or 10)
  int lane = threadIdx.x & 63;
  int g = lane >> 4;                   // edge group 0..3
  int t = lane & 15;                   // feature-quad index
  int node = (blockIdx.x * blockDim.x + threadIdx.x) >> 6;
  if (node >= n) return;
  float di = dinv[node];
  float4 acc = make_float4(0.f, 0.f, 0.f, 0.f);

  // self-loop (group 0 only)
  if (g == 0 && t < F4) {
    float4 v = h4f(h4[(size_t)node * F4 + t]);
    float s = di * di;
    acc.x = v.x * s; acc.y = v.y * s; acc.z = v.z * s; acc.w = v.w * s;
  }

  int beg = offset[node], end = offset[node + 1];
  int j = beg;
  // two 4-edge batches in flight
  for (; j + 8 <= end; j += 8) {
    int2 eA = sedge[j + g];
    int2 eB = sedge[j + 4 + g];
    ushort4 rA = (t < F4) ? h4[(size_t)eA.x * F4 + t] : make_ushort4(0, 0, 0, 0);
    ushort4 rB = (t < F4) ? h4[(size_t)eB.x * F4 + t] : make_ushort4(0, 0, 0, 0);
    float4 vA = h4f(rA), vB = h4f(rB);
    float nA = __int_as_float(eA.y), nB = __int_as_float(eB.y);
    acc.x = fmaf(vA.x, nA, acc.x); acc.y = fmaf(vA.y, nA, acc.y);
    acc.z = fmaf(vA.z, nA, acc.z); acc.w = fmaf(vA.w, nA, acc.w);
    acc.x = fmaf(vB.x, nB, acc.x); acc.y = fmaf(vB.y, nB, acc.y);
    acc.z = fmaf(vB.z, nB, acc.z); acc.w = fmaf(vB.w, nB, acc.w);
  }
  // masked 4-edge tail
  for (; j < end; j += 4) {
    int r = end - j;                   // 1..4 valid (else loop exited)
    int gi = (g < r) ? g : (r - 1);
    int2 e = sedge[j + gi];
    float nm = (g < r) ? __int_as_float(e.y) : 0.f;
    ushort4 rv = (t < F4) ? h4[(size_t)e.x * F4 + t] : make_ushort4(0, 0, 0, 0);
    float4 v = h4f(rv);
    acc.x = fmaf(v.x, nm, acc.x); acc.y = fmaf(v.y, nm, acc.y);
    acc.z = fmaf(v.z, nm, acc.z); acc.w = fmaf(v.w, nm, acc.w);
  }

  // reduce across the 4 groups
  acc.x += __shfl_xor(acc.x, 16); acc.y += __shfl_xor(acc.y, 16);
  acc.z += __shfl_xor(acc.z, 16); acc.w += __shfl_xor(acc.w, 16);
  acc.x += __shfl_xor(acc.x, 32); acc.y += __shfl_xor(acc.y, 32);
  acc.z += __shfl_xor(acc.z, 32); acc.w += __shfl_xor(acc.w, 32);

  if (lane < F4) {
    float4 b = bias4[lane];
    float4 rv = make_float4(acc.x + b.x, acc.y + b.y, acc.z + b.z, acc.w + b.w);
    if (RELU) {
      rv.x = fmaxf(rv.x, 0.f); rv.y = fmaxf(rv.y, 0.f);
      rv.z = fmaxf(rv.z, 0.f); rv.w = fmaxf(rv.w, 0.f);
    }
    out4[(size_t)node * F4 + lane] = rv;
  }
}

// ---------------- launch ----------------

extern "C" void kernel_launch(void* const* d_in, const int* in_sizes, int n_in,
                              void* d_out, int out_size, void* d_ws, size_t ws_size,
                              hipStream_t stream) {
  const float* x  = (const float*)d_in[0];
  const int*   ei = (const int*)d_in[1];
  const float* W1 = (const float*)d_in[2];
  const float* b1 = (const float*)d_in[3];
  const float* W2 = (const float*)d_in[4];
  const float* b2 = (const float*)d_in[5];
  float* out = (float*)d_out;

  const int F_IN = 128, HID = 64, C = 40;
  int N = in_sizes[0] / F_IN;
  int E = in_sizes[1] / 2;
  const int* src = ei;
  const int* dst = ei + E;
  int nbuck = (N + NPB - 1) >> NPB_SHIFT;   // 391 for N=100000

  char* w = (char*)d_ws;
  size_t o = 0;
  auto alloc = [&](size_t bytes) -> void* {
    void* p = w + o;
    o = (o + bytes + 255) & ~(size_t)255;
    return p;
  };
  float*    dinv   = (float*)alloc((size_t)N * 4);
  int*      count  = (int*)alloc((size_t)N * 4);
  int*      offset = (int*)alloc((size_t)(N + 1) * 4);
  int*      bsum   = (int*)alloc(1024 * 4);
  int*      bfill  = (int*)alloc((size_t)nbuck * 4);
  unsigned* tmp    = (unsigned*)alloc((size_t)E * 4);
  int2*     sedge  = (int2*)alloc((size_t)E * 8);
  __half*   h      = (__half*)alloc((size_t)N * HID * 2);   // fp16 gather source
  float*    h1     = (float*)alloc((size_t)N * HID * 4);    // fp32, streamed by gemm2
  __half*   h2     = (__half*)alloc((size_t)N * C * 2);     // fp16 gather source

  int nb = (N + 1023) / 1024;

  dim3 b256(256);
  dim3 gN((N + 255) / 256), gE((E + 255) / 256);

  // degree / offsets
  k_zero_i32<<<gN, b256, 0, stream>>>(count, N);
  k_count<<<gE, b256, 0, stream>>>(dst, count, E);
  k_dinv<<<gN, b256, 0, stream>>>(count, dinv, N);
  k_scan1<<<dim3(nb), dim3(1024), 0, stream>>>(count, offset, bsum, N);
  k_scan2<<<dim3(1), dim3(1024), 0, stream>>>(bsum, nb);
  k_scan3<<<gN, b256, 0, stream>>>(count, offset, bsum, N, E);

  // locality-aware CSR build
  k_bfill<<<dim3((nbuck + 255) / 256), b256, 0, stream>>>(offset, bfill, nbuck);
  k_partition<<<dim3((E + CHUNK - 1) / CHUNK), b256, 0, stream>>>(src, dst, bfill, tmp, E, nbuck);
  k_csr<<<dim3(nbuck), b256, 0, stream>>>(tmp, offset, dinv, sedge, N);

  // layer 1
  k_gemm<128, 64, true><<<dim3(768), b256, 0, stream>>>(x, W1, h, N);
  k_agg_v<64, true><<<dim3((N + 3) / 4), b256, 0, stream>>>(
      (const ushort4*)h, offset, sedge, dinv, (const float4*)b1, (float4*)h1, N);

  // layer 2
  k_gemm<64, 40, true><<<dim3(768), b256, 0, stream>>>(h1, W2, h2, N);
  k_agg_v<40, false><<<dim3((N + 3) / 4), b256, 0, stream>>>(
      (const ushort4*)h2, offset, sedge, dinv, (const float4*)b2, (float4*)out, N);
}

// Round 6
// 358.274 us; speedup vs baseline: 1.3594x; 1.2144x over previous
//
#include <hip/hip_runtime.h>
#include <hip/hip_fp16.h>
#include <cstdint>
#include <cstddef>

#define NPB_SHIFT 8                      // 256 dst-nodes per bucket
#define NPB (1 << NPB_SHIFT)
#define CHUNK 2048                       // edges per partition block

typedef _Float16 half8_t __attribute__((ext_vector_type(8)));
typedef _Float16 half4_t __attribute__((ext_vector_type(4)));
typedef float floatx4 __attribute__((ext_vector_type(4)));

__device__ inline float ush2f(unsigned short u) {
  __half_raw r; r.x = u;
  return __half2float(__half(r));
}
__device__ inline float4 h4f(ushort4 v) {
  return make_float4(ush2f(v.x), ush2f(v.y), ush2f(v.z), ush2f(v.w));
}

// ---------------- graph preprocessing ----------------

__global__ void k_zero_i32(int* __restrict__ p, int n) {
  int i = blockIdx.x * blockDim.x + threadIdx.x;
  if (i < n) p[i] = 0;
}

__global__ void k_count(const int* __restrict__ dst, int* __restrict__ count, int E) {
  int e = blockIdx.x * blockDim.x + threadIdx.x;
  if (e < E) atomicAdd(&count[dst[e]], 1);
}

__global__ void k_dinv(const int* __restrict__ count, float* __restrict__ dinv, int n) {
  int i = blockIdx.x * blockDim.x + threadIdx.x;
  if (i < n) dinv[i] = rsqrtf((float)(count[i] + 1));  // +1 self-loop
}

// inclusive scan of 1024-chunks
__global__ void k_scan1(const int* __restrict__ count, int* __restrict__ incl,
                        int* __restrict__ bsum, int n) {
  __shared__ int tmp[1024];
  int tid = threadIdx.x;
  int gid = blockIdx.x * 1024 + tid;
  int v = (gid < n) ? count[gid] : 0;
  tmp[tid] = v;
  __syncthreads();
  for (int off = 1; off < 1024; off <<= 1) {
    int t = (tid >= off) ? tmp[tid - off] : 0;
    __syncthreads();
    tmp[tid] += t;
    __syncthreads();
  }
  if (gid < n) incl[gid] = tmp[tid];
  if (tid == 1023) bsum[blockIdx.x] = tmp[tid];
}

__global__ void k_scan2(int* __restrict__ bsum, int nb) {
  __shared__ int tmp[1024];
  int tid = threadIdx.x;
  int v = (tid < nb) ? bsum[tid] : 0;
  tmp[tid] = v;
  __syncthreads();
  for (int off = 1; off < 1024; off <<= 1) {
    int t = (tid >= off) ? tmp[tid - off] : 0;
    __syncthreads();
    tmp[tid] += t;
    __syncthreads();
  }
  if (tid < nb) bsum[tid] = tmp[tid] - v;  // exclusive
}

__global__ void k_scan3(const int* __restrict__ count, int* __restrict__ offset,
                        const int* __restrict__ bsum, int n, int E) {
  int gid = blockIdx.x * blockDim.x + threadIdx.x;
  if (gid < n) offset[gid] = offset[gid] - count[gid] + bsum[gid >> 10];
  if (gid == 0) offset[n] = E;
}

__global__ void k_bfill(const int* __restrict__ offset, int* __restrict__ bfill, int nbuck) {
  int b = blockIdx.x * blockDim.x + threadIdx.x;
  if (b < nbuck) bfill[b] = offset[b << NPB_SHIFT];
}

// pass 1: LDS multisplit into coarse dst-buckets; packed (src<<8)|dst_local, 4B/edge
__global__ __launch_bounds__(256) void k_partition(const int* __restrict__ src,
                                                   const int* __restrict__ dst,
                                                   int* __restrict__ bfill,
                                                   unsigned* __restrict__ tmp,
                                                   int E, int nbuck) {
  __shared__ int cnt[512];
  __shared__ int base[512];
  __shared__ int cur[512];
  int tid = threadIdx.x;
  int cbase = blockIdx.x * CHUNK;
  for (int i = tid; i < nbuck; i += 256) { cnt[i] = 0; cur[i] = 0; }
  __syncthreads();
  int s[8], d[8];
  bool valid[8];
#pragma unroll
  for (int u = 0; u < 8; ++u) {
    int e = cbase + u * 256 + tid;
    valid[u] = e < E;
    s[u] = valid[u] ? src[e] : 0;
    d[u] = valid[u] ? dst[e] : 0;
    if (valid[u]) atomicAdd(&cnt[d[u] >> NPB_SHIFT], 1);
  }
  __syncthreads();
  for (int i = tid; i < nbuck; i += 256)
    if (cnt[i]) base[i] = atomicAdd(&bfill[i], cnt[i]);
  __syncthreads();
#pragma unroll
  for (int u = 0; u < 8; ++u) {
    if (valid[u]) {
      int b = d[u] >> NPB_SHIFT;
      int r = atomicAdd(&cur[b], 1);
      tmp[base[b] + r] = ((unsigned)s[u] << NPB_SHIFT) | (unsigned)(d[u] & (NPB - 1));
    }
  }
}

// pass 2: one block per bucket; LDS fill counters -> exact CSR, writes L2-local
__global__ __launch_bounds__(256) void k_csr(const unsigned* __restrict__ tmp,
                                             const int* __restrict__ offset,
                                             const float* __restrict__ dinv,
                                             int2* __restrict__ sedge, int N) {
  __shared__ int fillL[NPB];
  __shared__ float dloc[NPB];
  int b = blockIdx.x;
  int nbase = b << NPB_SHIFT;
  int nend = min(nbase + NPB, N);
  int nloc = nend - nbase;
  int tid = threadIdx.x;
  for (int i = tid; i < nloc; i += 256) {
    fillL[i] = offset[nbase + i];
    dloc[i] = dinv[nbase + i];
  }
  __syncthreads();
  int ebeg = offset[nbase];
  int eend = offset[nend];
  int j = ebeg + tid;
  for (; j + 3 * 256 < eend; j += 4 * 256) {
    unsigned p[4];
#pragma unroll
    for (int u = 0; u < 4; ++u) p[u] = tmp[j + u * 256];
    float dv[4];
#pragma unroll
    for (int u = 0; u < 4; ++u) dv[u] = dinv[p[u] >> NPB_SHIFT];
#pragma unroll
    for (int u = 0; u < 4; ++u) {
      int dl = p[u] & (NPB - 1);
      int pos = atomicAdd(&fillL[dl], 1);
      sedge[pos] = make_int2((int)(p[u] >> NPB_SHIFT), __float_as_int(dv[u] * dloc[dl]));
    }
  }
  for (; j < eend; j += 256) {
    unsigned p = tmp[j];
    int dl = p & (NPB - 1);
    int s = (int)(p >> NPB_SHIFT);
    int pos = atomicAdd(&fillL[dl], 1);
    sedge[pos] = make_int2(s, __float_as_int(dinv[s] * dloc[dl]));
  }
}

// ---------------- dense layers: MFMA 16x16x32 f16 ----------------
// M = output columns (A = W^T frags, VGPR-resident), N = 16 nodes per wave
// (B = x rows, coalesced float4 + cvt). D: col(lane&15)=node, row(quad*4+reg)
// = output col -> lane packs 4 consecutive cols of one node into an 8B store.
// MT = ceil(COLS/16), KC = K/32.
template <int K, int COLS, int MT, int KC>
__global__ __launch_bounds__(256) void k_gemm_mfma(const float* __restrict__ x,
                                                   const float* __restrict__ W,
                                                   _Float16* __restrict__ out, int n) {
  int lane = threadIdx.x & 63;
  int quad = lane >> 4;
  int l15 = lane & 15;
  int gwave = (blockIdx.x * blockDim.x + threadIdx.x) >> 6;
  int nwave = (gridDim.x * blockDim.x) >> 6;
  int ntiles = (n + 15) >> 4;

  // A[m][k] = W[k][mtile*16+m], m=l15, k=c*32+quad*8+j
  half8_t afrag[MT][KC];
#pragma unroll
  for (int m = 0; m < MT; ++m) {
    int colw = m * 16 + l15;
    if (colw > COLS - 1) colw = COLS - 1;   // clamp (partial last m-tile)
#pragma unroll
    for (int c = 0; c < KC; ++c) {
#pragma unroll
      for (int j = 0; j < 8; ++j) {
        int kk = c * 32 + quad * 8 + j;
        afrag[m][c][j] = (_Float16)W[kk * COLS + colw];
      }
    }
  }

  for (int tile = gwave; tile < ntiles; tile += nwave) {
    int node0 = tile << 4;
    int nodeB = node0 + l15;
    int nodeC = nodeB < n ? nodeB : n - 1;
    const float* xr = x + (size_t)nodeC * K;
    half8_t bfrag[KC];
#pragma unroll
    for (int c = 0; c < KC; ++c) {
      float4 lo = *(const float4*)(xr + c * 32 + quad * 8);
      float4 hi = *(const float4*)(xr + c * 32 + quad * 8 + 4);
      bfrag[c][0] = (_Float16)lo.x; bfrag[c][1] = (_Float16)lo.y;
      bfrag[c][2] = (_Float16)lo.z; bfrag[c][3] = (_Float16)lo.w;
      bfrag[c][4] = (_Float16)hi.x; bfrag[c][5] = (_Float16)hi.y;
      bfrag[c][6] = (_Float16)hi.z; bfrag[c][7] = (_Float16)hi.w;
    }
    floatx4 acc[MT];
#pragma unroll
    for (int m = 0; m < MT; ++m) acc[m] = (floatx4){0.f, 0.f, 0.f, 0.f};
#pragma unroll
    for (int c = 0; c < KC; ++c)
#pragma unroll
      for (int m = 0; m < MT; ++m)
        acc[m] = __builtin_amdgcn_mfma_f32_16x16x32_f16(afrag[m][c], bfrag[c], acc[m], 0, 0, 0);

    if (nodeB < n) {
#pragma unroll
      for (int m = 0; m < MT; ++m) {
        int colBase = m * 16 + quad * 4;
        if (colBase < COLS) {
          half4_t hv = {(_Float16)acc[m][0], (_Float16)acc[m][1],
                        (_Float16)acc[m][2], (_Float16)acc[m][3]};
          *(half4_t*)(out + (size_t)nodeB * COLS + colBase) = hv;
        }
      }
    }
  }
}

// ---------------- aggregation: 4 edges per wave-request ----------------
template <int F, bool RELU>
__global__ __launch_bounds__(256) void k_agg_v(const ushort4* __restrict__ h4,
                                               const int* __restrict__ offset,
                                               const int2* __restrict__ sedge,
                                               const float* __restrict__ dinv,
                                               const float4* __restrict__ bias4,
                                               float4* __restrict__ out4, int n) {
  constexpr int F4 = F / 4;
  int lane = threadIdx.x & 63;
  int g = lane >> 4;
  int t = lane & 15;
  int node = (blockIdx.x * blockDim.x + threadIdx.x) >> 6;
  if (node >= n) return;
  float di = dinv[node];
  float4 acc = make_float4(0.f, 0.f, 0.f, 0.f);

  if (g == 0 && t < F4) {
    float4 v = h4f(h4[(size_t)node * F4 + t]);
    float s = di * di;
    acc.x = v.x * s; acc.y = v.y * s; acc.z = v.z * s; acc.w = v.w * s;
  }

  int beg = offset[node], end = offset[node + 1];
  int j = beg;
  for (; j + 8 <= end; j += 8) {
    int2 eA = sedge[j + g];
    int2 eB = sedge[j + 4 + g];
    ushort4 rA = (t < F4) ? h4[(size_t)eA.x * F4 + t] : make_ushort4(0, 0, 0, 0);
    ushort4 rB = (t < F4) ? h4[(size_t)eB.x * F4 + t] : make_ushort4(0, 0, 0, 0);
    float4 vA = h4f(rA), vB = h4f(rB);
    float nA = __int_as_float(eA.y), nB = __int_as_float(eB.y);
    acc.x = fmaf(vA.x, nA, acc.x); acc.y = fmaf(vA.y, nA, acc.y);
    acc.z = fmaf(vA.z, nA, acc.z); acc.w = fmaf(vA.w, nA, acc.w);
    acc.x = fmaf(vB.x, nB, acc.x); acc.y = fmaf(vB.y, nB, acc.y);
    acc.z = fmaf(vB.z, nB, acc.z); acc.w = fmaf(vB.w, nB, acc.w);
  }
  for (; j < end; j += 4) {
    int r = end - j;
    int gi = (g < r) ? g : (r - 1);
    int2 e = sedge[j + gi];
    float nm = (g < r) ? __int_as_float(e.y) : 0.f;
    ushort4 rv = (t < F4) ? h4[(size_t)e.x * F4 + t] : make_ushort4(0, 0, 0, 0);
    float4 v = h4f(rv);
    acc.x = fmaf(v.x, nm, acc.x); acc.y = fmaf(v.y, nm, acc.y);
    acc.z = fmaf(v.z, nm, acc.z); acc.w = fmaf(v.w, nm, acc.w);
  }

  acc.x += __shfl_xor(acc.x, 16); acc.y += __shfl_xor(acc.y, 16);
  acc.z += __shfl_xor(acc.z, 16); acc.w += __shfl_xor(acc.w, 16);
  acc.x += __shfl_xor(acc.x, 32); acc.y += __shfl_xor(acc.y, 32);
  acc.z += __shfl_xor(acc.z, 32); acc.w += __shfl_xor(acc.w, 32);

  if (lane < F4) {
    float4 b = bias4[lane];
    float4 rv = make_float4(acc.x + b.x, acc.y + b.y, acc.z + b.z, acc.w + b.w);
    if (RELU) {
      rv.x = fmaxf(rv.x, 0.f); rv.y = fmaxf(rv.y, 0.f);
      rv.z = fmaxf(rv.z, 0.f); rv.w = fmaxf(rv.w, 0.f);
    }
    out4[(size_t)node * F4 + lane] = rv;
  }
}

// ---------------- launch ----------------

extern "C" void kernel_launch(void* const* d_in, const int* in_sizes, int n_in,
                              void* d_out, int out_size, void* d_ws, size_t ws_size,
                              hipStream_t stream) {
  const float* x  = (const float*)d_in[0];
  const int*   ei = (const int*)d_in[1];
  const float* W1 = (const float*)d_in[2];
  const float* b1 = (const float*)d_in[3];
  const float* W2 = (const float*)d_in[4];
  const float* b2 = (const float*)d_in[5];
  float* out = (float*)d_out;

  const int F_IN = 128, HID = 64, C = 40;
  int N = in_sizes[0] / F_IN;
  int E = in_sizes[1] / 2;
  const int* src = ei;
  const int* dst = ei + E;
  int nbuck = (N + NPB - 1) >> NPB_SHIFT;   // 391 for N=100000

  char* w = (char*)d_ws;
  size_t o = 0;
  auto alloc = [&](size_t bytes) -> void* {
    void* p = w + o;
    o = (o + bytes + 255) & ~(size_t)255;
    return p;
  };
  float*    dinv   = (float*)alloc((size_t)N * 4);
  int*      count  = (int*)alloc((size_t)N * 4);
  int*      offset = (int*)alloc((size_t)(N + 1) * 4);
  int*      bsum   = (int*)alloc(1024 * 4);
  int*      bfill  = (int*)alloc((size_t)nbuck * 4);
  unsigned* tmp    = (unsigned*)alloc((size_t)E * 4);
  int2*     sedge  = (int2*)alloc((size_t)E * 8);
  _Float16* h      = (_Float16*)alloc((size_t)N * HID * 2);  // fp16 gather source
  float*    h1     = (float*)alloc((size_t)N * HID * 4);     // fp32, streamed by gemm2
  _Float16* h2     = (_Float16*)alloc((size_t)N * C * 2);    // fp16 gather source

  int nb = (N + 1023) / 1024;

  dim3 b256(256);
  dim3 gN((N + 255) / 256), gE((E + 255) / 256);

  // degree / offsets
  k_zero_i32<<<gN, b256, 0, stream>>>(count, N);
  k_count<<<gE, b256, 0, stream>>>(dst, count, E);
  k_dinv<<<gN, b256, 0, stream>>>(count, dinv, N);
  k_scan1<<<dim3(nb), dim3(1024), 0, stream>>>(count, offset, bsum, N);
  k_scan2<<<dim3(1), dim3(1024), 0, stream>>>(bsum, nb);
  k_scan3<<<gN, b256, 0, stream>>>(count, offset, bsum, N, E);

  // locality-aware CSR build
  k_bfill<<<dim3((nbuck + 255) / 256), b256, 0, stream>>>(offset, bfill, nbuck);
  k_partition<<<dim3((E + CHUNK - 1) / CHUNK), b256, 0, stream>>>(src, dst, bfill, tmp, E, nbuck);
  k_csr<<<dim3(nbuck), b256, 0, stream>>>(tmp, offset, dinv, sedge, N);

  // layer 1: x(fp32,128) @ W1 -> h(fp16,64)
  k_gemm_mfma<128, 64, 4, 4><<<dim3(256), b256, 0, stream>>>(x, W1, h, N);
  k_agg_v<64, true><<<dim3((N + 3) / 4), b256, 0, stream>>>(
      (const ushort4*)h, offset, sedge, dinv, (const float4*)b1, (float4*)h1, N);

  // layer 2: h1(fp32,64) @ W2 -> h2(fp16,40)
  k_gemm_mfma<64, 40, 3, 2><<<dim3(256), b256, 0, stream>>>(h1, W2, h2, N);
  k_agg_v<40, false><<<dim3((N + 3) / 4), b256, 0, stream>>>(
      (const ushort4*)h2, offset, sedge, dinv, (const float4*)b2, (float4*)out, N);
}

// Round 7
// 298.660 us; speedup vs baseline: 1.6308x; 1.1996x over previous
//
#include <hip/hip_runtime.h>
#include <hip/hip_fp16.h>
#include <cstdint>
#include <cstddef>

#define NPB_SHIFT 8                      // 256 dst-nodes per bucket
#define NPB (1 << NPB_SHIFT)
#define CHUNK 2048                       // edges per partition block
#define BCHUNK 8192                      // edges per bucket-count block
// nbuck = ceil(N/256) must be <= 512 (N <= 131072) for the LDS arrays below.

typedef _Float16 half8_t __attribute__((ext_vector_type(8)));
typedef _Float16 half4_t __attribute__((ext_vector_type(4)));
typedef float floatx4 __attribute__((ext_vector_type(4)));

__device__ inline float ush2f(unsigned short u) {
  __half_raw r; r.x = u;
  return __half2float(__half(r));
}
__device__ inline float4 h4f(ushort4 v) {
  return make_float4(ush2f(v.x), ush2f(v.y), ush2f(v.z), ush2f(v.w));
}

// ---------------- graph preprocessing ----------------

__global__ void k_zero_i32(int* __restrict__ p, int n) {
  int i = blockIdx.x * blockDim.x + threadIdx.x;
  if (i < n) p[i] = 0;
}

// bucket histogram: LDS-aggregated, <=nbuck global atomics per block
__global__ __launch_bounds__(256) void k_bcount(const int* __restrict__ dst,
                                                int* __restrict__ btot, int E, int nbuck) {
  __shared__ int cnt[512];
  int tid = threadIdx.x;
  for (int i = tid; i < nbuck; i += 256) cnt[i] = 0;
  __syncthreads();
  int base = blockIdx.x * BCHUNK;
  int end = min(base + BCHUNK, E);
  for (int e = base + tid; e < end; e += 256) atomicAdd(&cnt[dst[e] >> NPB_SHIFT], 1);
  __syncthreads();
  for (int i = tid; i < nbuck; i += 256)
    if (cnt[i]) atomicAdd(&btot[i], cnt[i]);
}

// exclusive scan of bucket totals -> bucket bases (+ copy to bfill)
__global__ void k_bscan(const int* __restrict__ btot, int* __restrict__ bbase,
                        int* __restrict__ bfill, int nbuck, int E) {
  __shared__ int tmp[512];
  int tid = threadIdx.x;
  int v = (tid < nbuck) ? btot[tid] : 0;
  tmp[tid] = v;
  __syncthreads();
  for (int off = 1; off < 512; off <<= 1) {
    int t = (tid >= off) ? tmp[tid - off] : 0;
    __syncthreads();
    tmp[tid] += t;
    __syncthreads();
  }
  if (tid < nbuck) { int ex = tmp[tid] - v; bbase[tid] = ex; bfill[tid] = ex; }
  if (tid == 0) bbase[nbuck] = E;
}

// pass 1: LDS multisplit into coarse dst-buckets; packed (src<<8)|dst_local, 4B/edge
__global__ __launch_bounds__(256) void k_partition(const int* __restrict__ src,
                                                   const int* __restrict__ dst,
                                                   int* __restrict__ bfill,
                                                   unsigned* __restrict__ tmp,
                                                   int E, int nbuck) {
  __shared__ int cnt[512];
  __shared__ int base[512];
  __shared__ int cur[512];
  int tid = threadIdx.x;
  int cbase = blockIdx.x * CHUNK;
  for (int i = tid; i < nbuck; i += 256) { cnt[i] = 0; cur[i] = 0; }
  __syncthreads();
  int s[8], d[8];
  bool valid[8];
#pragma unroll
  for (int u = 0; u < 8; ++u) {
    int e = cbase + u * 256 + tid;
    valid[u] = e < E;
    s[u] = valid[u] ? src[e] : 0;
    d[u] = valid[u] ? dst[e] : 0;
    if (valid[u]) atomicAdd(&cnt[d[u] >> NPB_SHIFT], 1);
  }
  __syncthreads();
  for (int i = tid; i < nbuck; i += 256)
    if (cnt[i]) base[i] = atomicAdd(&bfill[i], cnt[i]);
  __syncthreads();
#pragma unroll
  for (int u = 0; u < 8; ++u) {
    if (valid[u]) {
      int b = d[u] >> NPB_SHIFT;
      int r = atomicAdd(&cur[b], 1);
      tmp[base[b] + r] = ((unsigned)s[u] << NPB_SHIFT) | (unsigned)(d[u] & (NPB - 1));
    }
  }
}

// per bucket: LDS degree count -> dinv + per-node offsets (no global atomics)
__global__ __launch_bounds__(256) void k_csr_count(const unsigned* __restrict__ tmp,
                                                   const int* __restrict__ bbase,
                                                   float* __restrict__ dinv,
                                                   int* __restrict__ offset,
                                                   int N, int E, int nbuck) {
  __shared__ int cnt[NPB];
  __shared__ int scan[NPB];
  int b = blockIdx.x, tid = threadIdx.x;
  int nbase = b << NPB_SHIFT;
  int nloc = min(NPB, N - nbase);
  cnt[tid] = 0;
  __syncthreads();
  int ebeg = bbase[b], eend = bbase[b + 1];
  for (int j = ebeg + tid; j < eend; j += 256) atomicAdd(&cnt[tmp[j] & (NPB - 1)], 1);
  __syncthreads();
  int v = cnt[tid];
  scan[tid] = v;
  __syncthreads();
  for (int off = 1; off < NPB; off <<= 1) {
    int t = (tid >= off) ? scan[tid - off] : 0;
    __syncthreads();
    scan[tid] += t;
    __syncthreads();
  }
  if (tid < nloc) {
    offset[nbase + tid] = ebeg + scan[tid] - v;   // exclusive
    dinv[nbase + tid] = rsqrtf((float)(v + 1));   // +1 self-loop
  }
  if (b == nbuck - 1 && tid == 0) offset[N] = E;
}

// per bucket: norms + exact CSR scatter (LDS fill counters, writes L2-local)
__global__ __launch_bounds__(256) void k_csr2(const unsigned* __restrict__ tmp,
                                              const int* __restrict__ offset,
                                              const float* __restrict__ dinv,
                                              int2* __restrict__ sedge, int N) {
  __shared__ int fillL[NPB];
  __shared__ float dloc[NPB];
  int b = blockIdx.x;
  int nbase = b << NPB_SHIFT;
  int nend = min(nbase + NPB, N);
  int nloc = nend - nbase;
  int tid = threadIdx.x;
  for (int i = tid; i < nloc; i += 256) {
    fillL[i] = offset[nbase + i];
    dloc[i] = dinv[nbase + i];
  }
  __syncthreads();
  int ebeg = offset[nbase];
  int eend = offset[nend];
  int j = ebeg + tid;
  for (; j + 3 * 256 < eend; j += 4 * 256) {
    unsigned p[4];
#pragma unroll
    for (int u = 0; u < 4; ++u) p[u] = tmp[j + u * 256];
    float dv[4];
#pragma unroll
    for (int u = 0; u < 4; ++u) dv[u] = dinv[p[u] >> NPB_SHIFT];
#pragma unroll
    for (int u = 0; u < 4; ++u) {
      int dl = p[u] & (NPB - 1);
      int pos = atomicAdd(&fillL[dl], 1);
      sedge[pos] = make_int2((int)(p[u] >> NPB_SHIFT), __float_as_int(dv[u] * dloc[dl]));
    }
  }
  for (; j < eend; j += 256) {
    unsigned p = tmp[j];
    int dl = p & (NPB - 1);
    int s = (int)(p >> NPB_SHIFT);
    int pos = atomicAdd(&fillL[dl], 1);
    sedge[pos] = make_int2(s, __float_as_int(dinv[s] * dloc[dl]));
  }
}

// ---------------- dense layers: MFMA 16x16x32 f16 ----------------
template <int K, int COLS, int MT, int KC>
__global__ __launch_bounds__(256) void k_gemm_mfma(const float* __restrict__ x,
                                                   const float* __restrict__ W,
                                                   _Float16* __restrict__ out, int n) {
  int lane = threadIdx.x & 63;
  int quad = lane >> 4;
  int l15 = lane & 15;
  int gwave = (blockIdx.x * blockDim.x + threadIdx.x) >> 6;
  int nwave = (gridDim.x * blockDim.x) >> 6;
  int ntiles = (n + 15) >> 4;

  half8_t afrag[MT][KC];
#pragma unroll
  for (int m = 0; m < MT; ++m) {
    int colw = m * 16 + l15;
    if (colw > COLS - 1) colw = COLS - 1;
#pragma unroll
    for (int c = 0; c < KC; ++c) {
#pragma unroll
      for (int j = 0; j < 8; ++j) {
        int kk = c * 32 + quad * 8 + j;
        afrag[m][c][j] = (_Float16)W[kk * COLS + colw];
      }
    }
  }

  for (int tile = gwave; tile < ntiles; tile += nwave) {
    int node0 = tile << 4;
    int nodeB = node0 + l15;
    int nodeC = nodeB < n ? nodeB : n - 1;
    const float* xr = x + (size_t)nodeC * K;
    half8_t bfrag[KC];
#pragma unroll
    for (int c = 0; c < KC; ++c) {
      float4 lo = *(const float4*)(xr + c * 32 + quad * 8);
      float4 hi = *(const float4*)(xr + c * 32 + quad * 8 + 4);
      bfrag[c][0] = (_Float16)lo.x; bfrag[c][1] = (_Float16)lo.y;
      bfrag[c][2] = (_Float16)lo.z; bfrag[c][3] = (_Float16)lo.w;
      bfrag[c][4] = (_Float16)hi.x; bfrag[c][5] = (_Float16)hi.y;
      bfrag[c][6] = (_Float16)hi.z; bfrag[c][7] = (_Float16)hi.w;
    }
    floatx4 acc[MT];
#pragma unroll
    for (int m = 0; m < MT; ++m) acc[m] = (floatx4){0.f, 0.f, 0.f, 0.f};
#pragma unroll
    for (int c = 0; c < KC; ++c)
#pragma unroll
      for (int m = 0; m < MT; ++m)
        acc[m] = __builtin_amdgcn_mfma_f32_16x16x32_f16(afrag[m][c], bfrag[c], acc[m], 0, 0, 0);

    if (nodeB < n) {
#pragma unroll
      for (int m = 0; m < MT; ++m) {
        int colBase = m * 16 + quad * 4;
        if (colBase < COLS) {
          half4_t hv = {(_Float16)acc[m][0], (_Float16)acc[m][1],
                        (_Float16)acc[m][2], (_Float16)acc[m][3]};
          *(half4_t*)(out + (size_t)nodeB * COLS + colBase) = hv;
        }
      }
    }
  }
}

// ---------------- aggregation: 4 edges per wave-request ----------------
template <int F, bool RELU>
__global__ __launch_bounds__(256) void k_agg_v(const ushort4* __restrict__ h4,
                                               const int* __restrict__ offset,
                                               const int2* __restrict__ sedge,
                                               const float* __restrict__ dinv,
                                               const float4* __restrict__ bias4,
                                               float4* __restrict__ out4, int n) {
  constexpr int F4 = F / 4;
  int lane = threadIdx.x & 63;
  int g = lane >> 4;
  int t = lane & 15;
  int node = (blockIdx.x * blockDim.x + threadIdx.x) >> 6;
  if (node >= n) return;
  float di = dinv[node];
  float4 acc = make_float4(0.f, 0.f, 0.f, 0.f);

  if (g == 0 && t < F4) {
    float4 v = h4f(h4[(size_t)node * F4 + t]);
    float s = di * di;
    acc.x = v.x * s; acc.y = v.y * s; acc.z = v.z * s; acc.w = v.w * s;
  }

  int beg = offset[node], end = offset[node + 1];
  int j = beg;
  for (; j + 8 <= end; j += 8) {
    int2 eA = sedge[j + g];
    int2 eB = sedge[j + 4 + g];
    ushort4 rA = (t < F4) ? h4[(size_t)eA.x * F4 + t] : make_ushort4(0, 0, 0, 0);
    ushort4 rB = (t < F4) ? h4[(size_t)eB.x * F4 + t] : make_ushort4(0, 0, 0, 0);
    float4 vA = h4f(rA), vB = h4f(rB);
    float nA = __int_as_float(eA.y), nB = __int_as_float(eB.y);
    acc.x = fmaf(vA.x, nA, acc.x); acc.y = fmaf(vA.y, nA, acc.y);
    acc.z = fmaf(vA.z, nA, acc.z); acc.w = fmaf(vA.w, nA, acc.w);
    acc.x = fmaf(vB.x, nB, acc.x); acc.y = fmaf(vB.y, nB, acc.y);
    acc.z = fmaf(vB.z, nB, acc.z); acc.w = fmaf(vB.w, nB, acc.w);
  }
  for (; j < end; j += 4) {
    int r = end - j;
    int gi = (g < r) ? g : (r - 1);
    int2 e = sedge[j + gi];
    float nm = (g < r) ? __int_as_float(e.y) : 0.f;
    ushort4 rv = (t < F4) ? h4[(size_t)e.x * F4 + t] : make_ushort4(0, 0, 0, 0);
    float4 v = h4f(rv);
    acc.x = fmaf(v.x, nm, acc.x); acc.y = fmaf(v.y, nm, acc.y);
    acc.z = fmaf(v.z, nm, acc.z); acc.w = fmaf(v.w, nm, acc.w);
  }

  acc.x += __shfl_xor(acc.x, 16); acc.y += __shfl_xor(acc.y, 16);
  acc.z += __shfl_xor(acc.z, 16); acc.w += __shfl_xor(acc.w, 16);
  acc.x += __shfl_xor(acc.x, 32); acc.y += __shfl_xor(acc.y, 32);
  acc.z += __shfl_xor(acc.z, 32); acc.w += __shfl_xor(acc.w, 32);

  if (lane < F4) {
    float4 b = bias4[lane];
    float4 rv = make_float4(acc.x + b.x, acc.y + b.y, acc.z + b.z, acc.w + b.w);
    if (RELU) {
      rv.x = fmaxf(rv.x, 0.f); rv.y = fmaxf(rv.y, 0.f);
      rv.z = fmaxf(rv.z, 0.f); rv.w = fmaxf(rv.w, 0.f);
    }
    out4[(size_t)node * F4 + lane] = rv;
  }
}

// ---------------- launch ----------------

extern "C" void kernel_launch(void* const* d_in, const int* in_sizes, int n_in,
                              void* d_out, int out_size, void* d_ws, size_t ws_size,
                              hipStream_t stream) {
  const float* x  = (const float*)d_in[0];
  const int*   ei = (const int*)d_in[1];
  const float* W1 = (const float*)d_in[2];
  const float* b1 = (const float*)d_in[3];
  const float* W2 = (const float*)d_in[4];
  const float* b2 = (const float*)d_in[5];
  float* out = (float*)d_out;

  const int F_IN = 128, HID = 64, C = 40;
  int N = in_sizes[0] / F_IN;
  int E = in_sizes[1] / 2;
  const int* src = ei;
  const int* dst = ei + E;
  int nbuck = (N + NPB - 1) >> NPB_SHIFT;   // 391 for N=100000

  char* w = (char*)d_ws;
  size_t o = 0;
  auto alloc = [&](size_t bytes) -> void* {
    void* p = w + o;
    o = (o + bytes + 255) & ~(size_t)255;
    return p;
  };
  float*    dinv   = (float*)alloc((size_t)N * 4);
  int*      offset = (int*)alloc((size_t)(N + 1) * 4);
  int*      btot   = (int*)alloc(512 * 4);
  int*      bbase  = (int*)alloc(513 * 4);
  int*      bfill  = (int*)alloc(512 * 4);
  unsigned* tmp    = (unsigned*)alloc((size_t)E * 4);
  int2*     sedge  = (int2*)alloc((size_t)E * 8);
  _Float16* h      = (_Float16*)alloc((size_t)N * HID * 2);
  float*    h1     = (float*)alloc((size_t)N * HID * 4);
  _Float16* h2     = (_Float16*)alloc((size_t)N * C * 2);

  dim3 b256(256);

  // bucket totals -> bases
  k_zero_i32<<<dim3(2), b256, 0, stream>>>(btot, 512);
  k_bcount<<<dim3((E + BCHUNK - 1) / BCHUNK), b256, 0, stream>>>(dst, btot, E, nbuck);
  k_bscan<<<dim3(1), dim3(512), 0, stream>>>(btot, bbase, bfill, nbuck, E);

  // partition + per-bucket CSR build (no global per-node atomics anywhere)
  k_partition<<<dim3((E + CHUNK - 1) / CHUNK), b256, 0, stream>>>(src, dst, bfill, tmp, E, nbuck);
  k_csr_count<<<dim3(nbuck), b256, 0, stream>>>(tmp, bbase, dinv, offset, N, E, nbuck);
  k_csr2<<<dim3(nbuck), b256, 0, stream>>>(tmp, offset, dinv, sedge, N);

  // layer 1: x(fp32,128) @ W1 -> h(fp16,64)
  k_gemm_mfma<128, 64, 4, 4><<<dim3(256), b256, 0, stream>>>(x, W1, h, N);
  k_agg_v<64, true><<<dim3((N + 3) / 4), b256, 0, stream>>>(
      (const ushort4*)h, offset, sedge, dinv, (const float4*)b1, (float4*)h1, N);

  // layer 2: h1(fp32,64) @ W2 -> h2(fp16,40)
  k_gemm_mfma<64, 40, 3, 2><<<dim3(256), b256, 0, stream>>>(h1, W2, h2, N);
  k_agg_v<40, false><<<dim3((N + 3) / 4), b256, 0, stream>>>(
      (const ushort4*)h2, offset, sedge, dinv, (const float4*)b2, (float4*)out, N);
}

// Round 8
// 284.907 us; speedup vs baseline: 1.7095x; 1.0483x over previous
//
#include <hip/hip_runtime.h>
#include <hip/hip_fp16.h>
#include <cstdint>
#include <cstddef>

#define NPB_SHIFT 8                      // 256 dst-nodes per bucket
#define NPB (1 << NPB_SHIFT)
#define CHUNK 4096                       // edges per partition block
#define BCHUNK 8192                      // edges per bucket-count block
// nbuck = ceil(N/256) must be <= 512 (N <= 131072) for the LDS arrays below.

typedef _Float16 half8_t __attribute__((ext_vector_type(8)));
typedef _Float16 half4_t __attribute__((ext_vector_type(4)));
typedef float floatx4 __attribute__((ext_vector_type(4)));

__device__ inline float ush2f(unsigned short u) {
  __half_raw r; r.x = u;
  return __half2float(__half(r));
}
__device__ inline void h8f(uint4 v, float* f) {
  f[0] = ush2f((unsigned short)(v.x & 0xffff)); f[1] = ush2f((unsigned short)(v.x >> 16));
  f[2] = ush2f((unsigned short)(v.y & 0xffff)); f[3] = ush2f((unsigned short)(v.y >> 16));
  f[4] = ush2f((unsigned short)(v.z & 0xffff)); f[5] = ush2f((unsigned short)(v.z >> 16));
  f[6] = ush2f((unsigned short)(v.w & 0xffff)); f[7] = ush2f((unsigned short)(v.w >> 16));
}

// ---------------- graph preprocessing ----------------

__global__ void k_zero_i32(int* __restrict__ p, int n) {
  int i = blockIdx.x * blockDim.x + threadIdx.x;
  if (i < n) p[i] = 0;
}

// bucket histogram: LDS-aggregated, <=nbuck global atomics per block
__global__ __launch_bounds__(256) void k_bcount(const int* __restrict__ dst,
                                                int* __restrict__ btot, int E, int nbuck) {
  __shared__ int cnt[512];
  int tid = threadIdx.x;
  for (int i = tid; i < nbuck; i += 256) cnt[i] = 0;
  __syncthreads();
  int base = blockIdx.x * BCHUNK;
  int end = min(base + BCHUNK, E);
  for (int e = base + tid; e < end; e += 256) atomicAdd(&cnt[dst[e] >> NPB_SHIFT], 1);
  __syncthreads();
  for (int i = tid; i < nbuck; i += 256)
    if (cnt[i]) atomicAdd(&btot[i], cnt[i]);
}

// exclusive scan of bucket totals -> bucket bases (+ copy to bfill)
__global__ void k_bscan(const int* __restrict__ btot, int* __restrict__ bbase,
                        int* __restrict__ bfill, int nbuck, int E) {
  __shared__ int tmp[512];
  int tid = threadIdx.x;
  int v = (tid < nbuck) ? btot[tid] : 0;
  tmp[tid] = v;
  __syncthreads();
  for (int off = 1; off < 512; off <<= 1) {
    int t = (tid >= off) ? tmp[tid - off] : 0;
    __syncthreads();
    tmp[tid] += t;
    __syncthreads();
  }
  if (tid < nbuck) { int ex = tmp[tid] - v; bbase[tid] = ex; bfill[tid] = ex; }
  if (tid == 0) bbase[nbuck] = E;
}

// pass 1: LDS multisplit into coarse dst-buckets; packed (src<<8)|dst_local, 4B/edge
__global__ __launch_bounds__(256) void k_partition(const int* __restrict__ src,
                                                   const int* __restrict__ dst,
                                                   int* __restrict__ bfill,
                                                   unsigned* __restrict__ tmp,
                                                   int E, int nbuck) {
  __shared__ int cnt[512];
  __shared__ int base[512];
  __shared__ int cur[512];
  int tid = threadIdx.x;
  int cbase = blockIdx.x * CHUNK;
  for (int i = tid; i < nbuck; i += 256) { cnt[i] = 0; cur[i] = 0; }
  __syncthreads();
  int s[16], d[16];
  bool valid[16];
#pragma unroll
  for (int u = 0; u < 16; ++u) {
    int e = cbase + u * 256 + tid;
    valid[u] = e < E;
    s[u] = valid[u] ? src[e] : 0;
    d[u] = valid[u] ? dst[e] : 0;
    if (valid[u]) atomicAdd(&cnt[d[u] >> NPB_SHIFT], 1);
  }
  __syncthreads();
  for (int i = tid; i < nbuck; i += 256)
    if (cnt[i]) base[i] = atomicAdd(&bfill[i], cnt[i]);
  __syncthreads();
#pragma unroll
  for (int u = 0; u < 16; ++u) {
    if (valid[u]) {
      int b = d[u] >> NPB_SHIFT;
      int r = atomicAdd(&cur[b], 1);
      tmp[base[b] + r] = ((unsigned)s[u] << NPB_SHIFT) | (unsigned)(d[u] & (NPB - 1));
    }
  }
}

// per bucket: LDS degree count -> dinv + per-node offsets (no global atomics)
__global__ __launch_bounds__(256) void k_csr_count(const unsigned* __restrict__ tmp,
                                                   const int* __restrict__ bbase,
                                                   float* __restrict__ dinv,
                                                   int* __restrict__ offset,
                                                   int N, int E, int nbuck) {
  __shared__ int cnt[NPB];
  __shared__ int scan[NPB];
  int b = blockIdx.x, tid = threadIdx.x;
  int nbase = b << NPB_SHIFT;
  int nloc = min(NPB, N - nbase);
  cnt[tid] = 0;
  __syncthreads();
  int ebeg = bbase[b], eend = bbase[b + 1];
  for (int j = ebeg + tid; j < eend; j += 256) atomicAdd(&cnt[tmp[j] & (NPB - 1)], 1);
  __syncthreads();
  int v = cnt[tid];
  scan[tid] = v;
  __syncthreads();
  for (int off = 1; off < NPB; off <<= 1) {
    int t = (tid >= off) ? scan[tid - off] : 0;
    __syncthreads();
    scan[tid] += t;
    __syncthreads();
  }
  if (tid < nloc) {
    offset[nbase + tid] = ebeg + scan[tid] - v;   // exclusive
    dinv[nbase + tid] = rsqrtf((float)(v + 1));   // +1 self-loop
  }
  if (b == nbuck - 1 && tid == 0) offset[N] = E;
}

// per bucket: norms + exact CSR scatter (LDS fill counters, writes L2-local)
__global__ __launch_bounds__(256) void k_csr2(const unsigned* __restrict__ tmp,
                                              const int* __restrict__ offset,
                                              const float* __restrict__ dinv,
                                              int2* __restrict__ sedge, int N) {
  __shared__ int fillL[NPB];
  __shared__ float dloc[NPB];
  int b = blockIdx.x;
  int nbase = b << NPB_SHIFT;
  int nend = min(nbase + NPB, N);
  int nloc = nend - nbase;
  int tid = threadIdx.x;
  for (int i = tid; i < nloc; i += 256) {
    fillL[i] = offset[nbase + i];
    dloc[i] = dinv[nbase + i];
  }
  __syncthreads();
  int ebeg = offset[nbase];
  int eend = offset[nend];
  int j = ebeg + tid;
  for (; j + 3 * 256 < eend; j += 4 * 256) {
    unsigned p[4];
#pragma unroll
    for (int u = 0; u < 4; ++u) p[u] = tmp[j + u * 256];
    float dv[4];
#pragma unroll
    for (int u = 0; u < 4; ++u) dv[u] = dinv[p[u] >> NPB_SHIFT];
#pragma unroll
    for (int u = 0; u < 4; ++u) {
      int dl = p[u] & (NPB - 1);
      int pos = atomicAdd(&fillL[dl], 1);
      sedge[pos] = make_int2((int)(p[u] >> NPB_SHIFT), __float_as_int(dv[u] * dloc[dl]));
    }
  }
  for (; j < eend; j += 256) {
    unsigned p = tmp[j];
    int dl = p & (NPB - 1);
    int s = (int)(p >> NPB_SHIFT);
    int pos = atomicAdd(&fillL[dl], 1);
    sedge[pos] = make_int2(s, __float_as_int(dinv[s] * dloc[dl]));
  }
}

// ---------------- dense layers: MFMA 16x16x32 f16 ----------------
// OS = output row stride (fp16 elems); may be padded past COLS.
template <int K, int COLS, int MT, int KC, int OS>
__global__ __launch_bounds__(256) void k_gemm_mfma(const float* __restrict__ x,
                                                   const float* __restrict__ W,
                                                   _Float16* __restrict__ out, int n) {
  int lane = threadIdx.x & 63;
  int quad = lane >> 4;
  int l15 = lane & 15;
  int gwave = (blockIdx.x * blockDim.x + threadIdx.x) >> 6;
  int nwave = (gridDim.x * blockDim.x) >> 6;
  int ntiles = (n + 15) >> 4;

  half8_t afrag[MT][KC];
#pragma unroll
  for (int m = 0; m < MT; ++m) {
    int colw = m * 16 + l15;
    if (colw > COLS - 1) colw = COLS - 1;
#pragma unroll
    for (int c = 0; c < KC; ++c) {
#pragma unroll
      for (int j = 0; j < 8; ++j) {
        int kk = c * 32 + quad * 8 + j;
        afrag[m][c][j] = (_Float16)W[kk * COLS + colw];
      }
    }
  }

  for (int tile = gwave; tile < ntiles; tile += nwave) {
    int node0 = tile << 4;
    int nodeB = node0 + l15;
    int nodeC = nodeB < n ? nodeB : n - 1;
    const float* xr = x + (size_t)nodeC * K;
    half8_t bfrag[KC];
#pragma unroll
    for (int c = 0; c < KC; ++c) {
      float4 lo = *(const float4*)(xr + c * 32 + quad * 8);
      float4 hi = *(const float4*)(xr + c * 32 + quad * 8 + 4);
      bfrag[c][0] = (_Float16)lo.x; bfrag[c][1] = (_Float16)lo.y;
      bfrag[c][2] = (_Float16)lo.z; bfrag[c][3] = (_Float16)lo.w;
      bfrag[c][4] = (_Float16)hi.x; bfrag[c][5] = (_Float16)hi.y;
      bfrag[c][6] = (_Float16)hi.z; bfrag[c][7] = (_Float16)hi.w;
    }
    floatx4 acc[MT];
#pragma unroll
    for (int m = 0; m < MT; ++m) acc[m] = (floatx4){0.f, 0.f, 0.f, 0.f};
#pragma unroll
    for (int c = 0; c < KC; ++c)
#pragma unroll
      for (int m = 0; m < MT; ++m)
        acc[m] = __builtin_amdgcn_mfma_f32_16x16x32_f16(afrag[m][c], bfrag[c], acc[m], 0, 0, 0);

    if (nodeB < n) {
#pragma unroll
      for (int m = 0; m < MT; ++m) {
        int colBase = m * 16 + quad * 4;
        if (colBase < OS) {
          half4_t hv = {(_Float16)acc[m][0], (_Float16)acc[m][1],
                        (_Float16)acc[m][2], (_Float16)acc[m][3]};
          *(half4_t*)(out + (size_t)nodeB * OS + colBase) = hv;
        }
      }
    }
  }
}

// ---------------- aggregation: 8 edges per gather instruction ----------------
// Wave = 8 groups x 8 lanes. Group g handles one edge; lane t loads uint4 =
// 8 fp16 feats (16B). S8 = source row stride in uint4 units (padded for F=40).
// Reduce across groups via shfl_xor(8,16,32); lanes 0..F/8-1 store 2x float4.
template <int F, int S8, bool RELU>
__global__ __launch_bounds__(256) void k_agg_v8(const uint4* __restrict__ h8,
                                                const int* __restrict__ offset,
                                                const int2* __restrict__ sedge,
                                                const float* __restrict__ dinv,
                                                const float* __restrict__ bias,
                                                float* __restrict__ outp, int n) {
  constexpr int F8 = F / 8;            // used octets per row (8 or 5)
  int lane = threadIdx.x & 63;
  int g = lane >> 3;                   // edge group 0..7
  int t = lane & 7;                    // feature octet
  int node = (blockIdx.x * blockDim.x + threadIdx.x) >> 6;
  if (node >= n) return;
  bool tv = t < F8;
  float di = dinv[node];
  float acc[8];
#pragma unroll
  for (int i = 0; i < 8; ++i) acc[i] = 0.f;

  if (g == 0 && tv) {
    float v[8];
    h8f(h8[(size_t)node * S8 + t], v);
    float s = di * di;
#pragma unroll
    for (int i = 0; i < 8; ++i) acc[i] = v[i] * s;
  }

  int beg = offset[node], end = offset[node + 1];
  int j = beg;
  // two 8-edge batches in flight
  for (; j + 16 <= end; j += 16) {
    int2 eA = sedge[j + g];
    int2 eB = sedge[j + 8 + g];
    uint4 rA = tv ? h8[(size_t)eA.x * S8 + t] : make_uint4(0, 0, 0, 0);
    uint4 rB = tv ? h8[(size_t)eB.x * S8 + t] : make_uint4(0, 0, 0, 0);
    float vA[8], vB[8];
    h8f(rA, vA); h8f(rB, vB);
    float nA = __int_as_float(eA.y), nB = __int_as_float(eB.y);
#pragma unroll
    for (int i = 0; i < 8; ++i) acc[i] = fmaf(vA[i], nA, acc[i]);
#pragma unroll
    for (int i = 0; i < 8; ++i) acc[i] = fmaf(vB[i], nB, acc[i]);
  }
  for (; j + 8 <= end; j += 8) {
    int2 e = sedge[j + g];
    uint4 rv = tv ? h8[(size_t)e.x * S8 + t] : make_uint4(0, 0, 0, 0);
    float v[8];
    h8f(rv, v);
    float nm = __int_as_float(e.y);
#pragma unroll
    for (int i = 0; i < 8; ++i) acc[i] = fmaf(v[i], nm, acc[i]);
  }
  // masked tail: 1..7 valid edges
  for (; j < end; j += 8) {
    int r = end - j;
    int gi = (g < r) ? g : (r - 1);
    int2 e = sedge[j + gi];
    float nm = (g < r) ? __int_as_float(e.y) : 0.f;
    uint4 rv = tv ? h8[(size_t)e.x * S8 + t] : make_uint4(0, 0, 0, 0);
    float v[8];
    h8f(rv, v);
#pragma unroll
    for (int i = 0; i < 8; ++i) acc[i] = fmaf(v[i], nm, acc[i]);
  }

  // reduce across the 8 groups
#pragma unroll
  for (int i = 0; i < 8; ++i) acc[i] += __shfl_xor(acc[i], 8);
#pragma unroll
  for (int i = 0; i < 8; ++i) acc[i] += __shfl_xor(acc[i], 16);
#pragma unroll
  for (int i = 0; i < 8; ++i) acc[i] += __shfl_xor(acc[i], 32);

  if (lane < F8) {
    const float* bb = bias + lane * 8;
    float4 r0 = make_float4(acc[0] + bb[0], acc[1] + bb[1], acc[2] + bb[2], acc[3] + bb[3]);
    float4 r1 = make_float4(acc[4] + bb[4], acc[5] + bb[5], acc[6] + bb[6], acc[7] + bb[7]);
    if (RELU) {
      r0.x = fmaxf(r0.x, 0.f); r0.y = fmaxf(r0.y, 0.f);
      r0.z = fmaxf(r0.z, 0.f); r0.w = fmaxf(r0.w, 0.f);
      r1.x = fmaxf(r1.x, 0.f); r1.y = fmaxf(r1.y, 0.f);
      r1.z = fmaxf(r1.z, 0.f); r1.w = fmaxf(r1.w, 0.f);
    }
    float4* o4 = (float4*)(outp + (size_t)node * F + lane * 8);
    o4[0] = r0; o4[1] = r1;
  }
}

// ---------------- launch ----------------

extern "C" void kernel_launch(void* const* d_in, const int* in_sizes, int n_in,
                              void* d_out, int out_size, void* d_ws, size_t ws_size,
                              hipStream_t stream) {
  const float* x  = (const float*)d_in[0];
  const int*   ei = (const int*)d_in[1];
  const float* W1 = (const float*)d_in[2];
  const float* b1 = (const float*)d_in[3];
  const float* W2 = (const float*)d_in[4];
  const float* b2 = (const float*)d_in[5];
  float* out = (float*)d_out;

  const int F_IN = 128, HID = 64, C = 40, CPAD = 48;
  int N = in_sizes[0] / F_IN;
  int E = in_sizes[1] / 2;
  const int* src = ei;
  const int* dst = ei + E;
  int nbuck = (N + NPB - 1) >> NPB_SHIFT;   // 391 for N=100000

  char* w = (char*)d_ws;
  size_t o = 0;
  auto alloc = [&](size_t bytes) -> void* {
    void* p = w + o;
    o = (o + bytes + 255) & ~(size_t)255;
    return p;
  };
  float*    dinv   = (float*)alloc((size_t)N * 4);
  int*      offset = (int*)alloc((size_t)(N + 1) * 4);
  int*      btot   = (int*)alloc(512 * 4);
  int*      bbase  = (int*)alloc(513 * 4);
  int*      bfill  = (int*)alloc(512 * 4);
  unsigned* tmp    = (unsigned*)alloc((size_t)E * 4);
  int2*     sedge  = (int2*)alloc((size_t)E * 8);
  _Float16* h      = (_Float16*)alloc((size_t)N * HID * 2);    // fp16, stride 64
  float*    h1     = (float*)alloc((size_t)N * HID * 4);       // fp32, streamed by gemm2
  _Float16* h2     = (_Float16*)alloc((size_t)N * CPAD * 2);   // fp16, stride 48 (padded)

  dim3 b256(256);

  // bucket totals -> bases
  k_zero_i32<<<dim3(2), b256, 0, stream>>>(btot, 512);
  k_bcount<<<dim3((E + BCHUNK - 1) / BCHUNK), b256, 0, stream>>>(dst, btot, E, nbuck);
  k_bscan<<<dim3(1), dim3(512), 0, stream>>>(btot, bbase, bfill, nbuck, E);

  // partition + per-bucket CSR build (no global per-node atomics anywhere)
  k_partition<<<dim3((E + CHUNK - 1) / CHUNK), b256, 0, stream>>>(src, dst, bfill, tmp, E, nbuck);
  k_csr_count<<<dim3(nbuck), b256, 0, stream>>>(tmp, bbase, dinv, offset, N, E, nbuck);
  k_csr2<<<dim3(nbuck), b256, 0, stream>>>(tmp, offset, dinv, sedge, N);

  // layer 1: x(fp32,128) @ W1 -> h(fp16, stride 64)
  k_gemm_mfma<128, 64, 4, 4, 64><<<dim3(256), b256, 0, stream>>>(x, W1, h, N);
  k_agg_v8<64, 8, true><<<dim3((N + 3) / 4), b256, 0, stream>>>(
      (const uint4*)h, offset, sedge, dinv, b1, h1, N);

  // layer 2: h1(fp32,64) @ W2 -> h2(fp16, stride 48 padded)
  k_gemm_mfma<64, 40, 3, 2, 48><<<dim3(256), b256, 0, stream>>>(h1, W2, h2, N);
  k_agg_v8<40, 6, false><<<dim3((N + 3) / 4), b256, 0, stream>>>(
      (const uint4*)h2, offset, sedge, dinv, b2, out, N);
}

// Round 10
// 269.729 us; speedup vs baseline: 1.8057x; 1.0563x over previous
//
#include <hip/hip_runtime.h>
#include <hip/hip_fp16.h>
#include <cstdint>
#include <cstddef>

#define NPB_SHIFT 8                      // 256 dst-nodes per bucket
#define NPB (1 << NPB_SHIFT)
#define CHUNK 4096                       // edges per partition block
#define BCHUNK 8192                      // edges per bucket-count block
// nbuck = ceil(N/256) must be <= 512 (N <= 131072) for the LDS arrays below.

typedef _Float16 half8_t __attribute__((ext_vector_type(8)));
typedef _Float16 half4_t __attribute__((ext_vector_type(4)));
typedef float floatx4 __attribute__((ext_vector_type(4)));

__device__ inline float ush2f(unsigned short u) {
  __half_raw r; r.x = u;
  return __half2float(__half(r));
}
__device__ inline void h8f(uint4 v, float* f) {
  f[0] = ush2f((unsigned short)(v.x & 0xffff)); f[1] = ush2f((unsigned short)(v.x >> 16));
  f[2] = ush2f((unsigned short)(v.y & 0xffff)); f[3] = ush2f((unsigned short)(v.y >> 16));
  f[4] = ush2f((unsigned short)(v.z & 0xffff)); f[5] = ush2f((unsigned short)(v.z >> 16));
  f[6] = ush2f((unsigned short)(v.w & 0xffff)); f[7] = ush2f((unsigned short)(v.w >> 16));
}

// ---------------- graph preprocessing ----------------

// bucket histogram: LDS-aggregated, <=nbuck global atomics per block
__global__ __launch_bounds__(256) void k_bcount(const int* __restrict__ dst,
                                                int* __restrict__ btot, int E, int nbuck) {
  __shared__ int cnt[512];
  int tid = threadIdx.x;
  for (int i = tid; i < nbuck; i += 256) cnt[i] = 0;
  __syncthreads();
  int base = blockIdx.x * BCHUNK;
  int end = min(base + BCHUNK, E);
  for (int e = base + tid; e < end; e += 256) atomicAdd(&cnt[dst[e] >> NPB_SHIFT], 1);
  __syncthreads();
  for (int i = tid; i < nbuck; i += 256)
    if (cnt[i]) atomicAdd(&btot[i], cnt[i]);
}

// exclusive scan of bucket totals -> bucket bases (+ copy to bfill)
__global__ void k_bscan(const int* __restrict__ btot, int* __restrict__ bbase,
                        int* __restrict__ bfill, int nbuck, int E) {
  __shared__ int tmp[512];
  int tid = threadIdx.x;
  int v = (tid < nbuck) ? btot[tid] : 0;
  tmp[tid] = v;
  __syncthreads();
  for (int off = 1; off < 512; off <<= 1) {
    int t = (tid >= off) ? tmp[tid - off] : 0;
    __syncthreads();
    tmp[tid] += t;
    __syncthreads();
  }
  if (tid < nbuck) { int ex = tmp[tid] - v; bbase[tid] = ex; bfill[tid] = ex; }
  if (tid == 0) bbase[nbuck] = E;
}

// pass 1: LDS multisplit into coarse dst-buckets; packed (src<<8)|dst_local, 4B/edge
__global__ __launch_bounds__(256) void k_partition(const int* __restrict__ src,
                                                   const int* __restrict__ dst,
                                                   int* __restrict__ bfill,
                                                   unsigned* __restrict__ tmp,
                                                   int E, int nbuck) {
  __shared__ int cnt[512];
  __shared__ int base[512];
  __shared__ int cur[512];
  int tid = threadIdx.x;
  int cbase = blockIdx.x * CHUNK;
  for (int i = tid; i < nbuck; i += 256) { cnt[i] = 0; cur[i] = 0; }
  __syncthreads();
  int s[16], d[16];
  bool valid[16];
#pragma unroll
  for (int u = 0; u < 16; ++u) {
    int e = cbase + u * 256 + tid;
    valid[u] = e < E;
    s[u] = valid[u] ? src[e] : 0;
    d[u] = valid[u] ? dst[e] : 0;
    if (valid[u]) atomicAdd(&cnt[d[u] >> NPB_SHIFT], 1);
  }
  __syncthreads();
  for (int i = tid; i < nbuck; i += 256)
    if (cnt[i]) base[i] = atomicAdd(&bfill[i], cnt[i]);
  __syncthreads();
#pragma unroll
  for (int u = 0; u < 16; ++u) {
    if (valid[u]) {
      int b = d[u] >> NPB_SHIFT;
      int r = atomicAdd(&cur[b], 1);
      tmp[base[b] + r] = ((unsigned)s[u] << NPB_SHIFT) | (unsigned)(d[u] & (NPB - 1));
    }
  }
}

// per bucket (merged): LDS degree count -> dinv + offsets, then src-only CSR
// scatter. No remote-node data needed since norms are folded into the GEMMs.
__global__ __launch_bounds__(256) void k_csr_build(const unsigned* __restrict__ tmp,
                                                   const int* __restrict__ bbase,
                                                   float* __restrict__ dinv,
                                                   int* __restrict__ offset,
                                                   int* __restrict__ ssrc,
                                                   int N, int E, int nbuck) {
  __shared__ int cnt[NPB];
  __shared__ int scan[NPB];
  __shared__ int fillL[NPB];
  int b = blockIdx.x, tid = threadIdx.x;
  int nbase = b << NPB_SHIFT;
  int nloc = min(NPB, N - nbase);
  cnt[tid] = 0;
  __syncthreads();
  int ebeg = bbase[b], eend = bbase[b + 1];
  for (int j = ebeg + tid; j < eend; j += 256) atomicAdd(&cnt[tmp[j] & (NPB - 1)], 1);
  __syncthreads();
  int v = cnt[tid];
  scan[tid] = v;
  __syncthreads();
  for (int off = 1; off < NPB; off <<= 1) {
    int t = (tid >= off) ? scan[tid - off] : 0;
    __syncthreads();
    scan[tid] += t;
    __syncthreads();
  }
  int myoff = ebeg + scan[tid] - v;   // exclusive
  fillL[tid] = myoff;
  if (tid < nloc) {
    offset[nbase + tid] = myoff;
    dinv[nbase + tid] = rsqrtf((float)(v + 1));   // +1 self-loop
  }
  if (b == nbuck - 1 && tid == 0) offset[N] = E;
  __syncthreads();
  // scatter src indices into exact CSR slots (LDS fill counters, L2-local writes)
  int j = ebeg + tid;
  for (; j + 3 * 256 < eend; j += 4 * 256) {
    unsigned p[4];
#pragma unroll
    for (int u = 0; u < 4; ++u) p[u] = tmp[j + u * 256];
#pragma unroll
    for (int u = 0; u < 4; ++u) {
      int pos = atomicAdd(&fillL[p[u] & (NPB - 1)], 1);
      ssrc[pos] = (int)(p[u] >> NPB_SHIFT);
    }
  }
  for (; j < eend; j += 256) {
    unsigned p = tmp[j];
    int pos = atomicAdd(&fillL[p & (NPB - 1)], 1);
    ssrc[pos] = (int)(p >> NPB_SHIFT);
  }
}

// ---------------- dense layers: MFMA 16x16x32 f16, output scaled by dinv ------
// Writes g[node] = dinv[node] * (x @ W)[node] as fp16, row stride OS.
template <int K, int COLS, int MT, int KC, int OS>
__global__ __launch_bounds__(256) void k_gemm_mfma(const float* __restrict__ x,
                                                   const float* __restrict__ W,
                                                   const float* __restrict__ dinv,
                                                   _Float16* __restrict__ out, int n) {
  int lane = threadIdx.x & 63;
  int quad = lane >> 4;
  int l15 = lane & 15;
  int gwave = (blockIdx.x * blockDim.x + threadIdx.x) >> 6;
  int nwave = (gridDim.x * blockDim.x) >> 6;
  int ntiles = (n + 15) >> 4;

  half8_t afrag[MT][KC];
#pragma unroll
  for (int m = 0; m < MT; ++m) {
    int colw = m * 16 + l15;
    if (colw > COLS - 1) colw = COLS - 1;
#pragma unroll
    for (int c = 0; c < KC; ++c) {
#pragma unroll
      for (int j = 0; j < 8; ++j) {
        int kk = c * 32 + quad * 8 + j;
        afrag[m][c][j] = (_Float16)W[kk * COLS + colw];
      }
    }
  }

  for (int tile = gwave; tile < ntiles; tile += nwave) {
    int node0 = tile << 4;
    int nodeB = node0 + l15;
    int nodeC = nodeB < n ? nodeB : n - 1;
    const float* xr = x + (size_t)nodeC * K;
    float dv = dinv[nodeC];
    half8_t bfrag[KC];
#pragma unroll
    for (int c = 0; c < KC; ++c) {
      float4 lo = *(const float4*)(xr + c * 32 + quad * 8);
      float4 hi = *(const float4*)(xr + c * 32 + quad * 8 + 4);
      bfrag[c][0] = (_Float16)lo.x; bfrag[c][1] = (_Float16)lo.y;
      bfrag[c][2] = (_Float16)lo.z; bfrag[c][3] = (_Float16)lo.w;
      bfrag[c][4] = (_Float16)hi.x; bfrag[c][5] = (_Float16)hi.y;
      bfrag[c][6] = (_Float16)hi.z; bfrag[c][7] = (_Float16)hi.w;
    }
    floatx4 acc[MT];
#pragma unroll
    for (int m = 0; m < MT; ++m) acc[m] = (floatx4){0.f, 0.f, 0.f, 0.f};
#pragma unroll
    for (int c = 0; c < KC; ++c)
#pragma unroll
      for (int m = 0; m < MT; ++m)
        acc[m] = __builtin_amdgcn_mfma_f32_16x16x32_f16(afrag[m][c], bfrag[c], acc[m], 0, 0, 0);

    if (nodeB < n) {
#pragma unroll
      for (int m = 0; m < MT; ++m) {
        int colBase = m * 16 + quad * 4;
        if (colBase < COLS) {
          half4_t hv = {(_Float16)(acc[m][0] * dv), (_Float16)(acc[m][1] * dv),
                        (_Float16)(acc[m][2] * dv), (_Float16)(acc[m][3] * dv)};
          *(half4_t*)(out + (size_t)nodeB * OS + colBase) = hv;
        }
      }
    }
  }
}

// ---------------- aggregation: unweighted sum of g rows ----------------
// Wave = 8 groups x 8 lanes; group g handles one edge, lane t loads uint4 =
// 8 fp16 feats (16B). out = dinv[node]*(g[node] + sum g[src]) + bias.
// Self term enters acc as plain g[node]: final *dinv makes it dinv^2*h. 
// S8 = row stride in uint4 units (8 for F=64, 5 for F=40).
template <int F, int S8, bool RELU>
__global__ __launch_bounds__(256) void k_agg_v8(const uint4* __restrict__ h8,
                                                const int* __restrict__ offset,
                                                const int* __restrict__ ssrc,
                                                const float* __restrict__ dinv,
                                                const float* __restrict__ bias,
                                                float* __restrict__ outp, int n) {
  constexpr int F8 = F / 8;            // used octets per row (8 or 5)
  int lane = threadIdx.x & 63;
  int g = lane >> 3;                   // edge group 0..7
  int t = lane & 7;                    // feature octet
  int node = (blockIdx.x * blockDim.x + threadIdx.x) >> 6;
  if (node >= n) return;
  bool tv = t < F8;
  float di = dinv[node];
  float acc[8];
#pragma unroll
  for (int i = 0; i < 8; ++i) acc[i] = 0.f;

  if (g == 0 && tv) {                  // self-loop term: g[node] (NOT *di here)
    float v[8];
    h8f(h8[(size_t)node * S8 + t], v);
#pragma unroll
    for (int i = 0; i < 8; ++i) acc[i] = v[i];
  }

  int beg = offset[node], end = offset[node + 1];
  int j = beg;
  for (; j + 16 <= end; j += 16) {
    int sA = ssrc[j + g];
    int sB = ssrc[j + 8 + g];
    uint4 rA = tv ? h8[(size_t)sA * S8 + t] : make_uint4(0, 0, 0, 0);
    uint4 rB = tv ? h8[(size_t)sB * S8 + t] : make_uint4(0, 0, 0, 0);
    float vA[8], vB[8];
    h8f(rA, vA); h8f(rB, vB);
#pragma unroll
    for (int i = 0; i < 8; ++i) acc[i] += vA[i] + vB[i];
  }
  for (; j + 8 <= end; j += 8) {
    int s = ssrc[j + g];
    uint4 rv = tv ? h8[(size_t)s * S8 + t] : make_uint4(0, 0, 0, 0);
    float v[8];
    h8f(rv, v);
#pragma unroll
    for (int i = 0; i < 8; ++i) acc[i] += v[i];
  }
  // masked tail: 1..7 valid edges
  if (j < end) {
    int r = end - j;
    int gi = (g < r) ? g : (r - 1);
    int s = ssrc[j + gi];
    uint4 rv = (tv && g < r) ? h8[(size_t)s * S8 + t] : make_uint4(0, 0, 0, 0);
    float v[8];
    h8f(rv, v);
#pragma unroll
    for (int i = 0; i < 8; ++i) acc[i] += v[i];
  }

  // reduce across the 8 groups
#pragma unroll
  for (int i = 0; i < 8; ++i) acc[i] += __shfl_xor(acc[i], 8);
#pragma unroll
  for (int i = 0; i < 8; ++i) acc[i] += __shfl_xor(acc[i], 16);
#pragma unroll
  for (int i = 0; i < 8; ++i) acc[i] += __shfl_xor(acc[i], 32);

  if (lane < F8) {
    const float* bb = bias + lane * 8;
    float4 r0 = make_float4(fmaf(acc[0], di, bb[0]), fmaf(acc[1], di, bb[1]),
                            fmaf(acc[2], di, bb[2]), fmaf(acc[3], di, bb[3]));
    float4 r1 = make_float4(fmaf(acc[4], di, bb[4]), fmaf(acc[5], di, bb[5]),
                            fmaf(acc[6], di, bb[6]), fmaf(acc[7], di, bb[7]));
    if (RELU) {
      r0.x = fmaxf(r0.x, 0.f); r0.y = fmaxf(r0.y, 0.f);
      r0.z = fmaxf(r0.z, 0.f); r0.w = fmaxf(r0.w, 0.f);
      r1.x = fmaxf(r1.x, 0.f); r1.y = fmaxf(r1.y, 0.f);
      r1.z = fmaxf(r1.z, 0.f); r1.w = fmaxf(r1.w, 0.f);
    }
    float4* o4 = (float4*)(outp + (size_t)node * F + lane * 8);
    o4[0] = r0; o4[1] = r1;
  }
}

// ---------------- launch ----------------

extern "C" void kernel_launch(void* const* d_in, const int* in_sizes, int n_in,
                              void* d_out, int out_size, void* d_ws, size_t ws_size,
                              hipStream_t stream) {
  const float* x  = (const float*)d_in[0];
  const int*   ei = (const int*)d_in[1];
  const float* W1 = (const float*)d_in[2];
  const float* b1 = (const float*)d_in[3];
  const float* W2 = (const float*)d_in[4];
  const float* b2 = (const float*)d_in[5];
  float* out = (float*)d_out;

  const int F_IN = 128, HID = 64, C = 40;
  int N = in_sizes[0] / F_IN;
  int E = in_sizes[1] / 2;
  const int* src = ei;
  const int* dst = ei + E;
  int nbuck = (N + NPB - 1) >> NPB_SHIFT;   // 391 for N=100000

  char* w = (char*)d_ws;
  size_t o = 0;
  auto alloc = [&](size_t bytes) -> void* {
    void* p = w + o;
    o = (o + bytes + 255) & ~(size_t)255;
    return p;
  };
  float*    dinv   = (float*)alloc((size_t)N * 4);
  int*      offset = (int*)alloc((size_t)(N + 1) * 4);
  int*      btot   = (int*)alloc(512 * 4);
  int*      bbase  = (int*)alloc(513 * 4);
  int*      bfill  = (int*)alloc(512 * 4);
  unsigned* tmp    = (unsigned*)alloc((size_t)E * 4);
  int*      ssrc   = (int*)alloc((size_t)E * 4);
  _Float16* g1     = (_Float16*)alloc((size_t)N * HID * 2);   // dinv*(xW1), stride 64
  float*    h1     = (float*)alloc((size_t)N * HID * 4);      // fp32, streamed by gemm2
  _Float16* g2     = (_Float16*)alloc((size_t)N * C * 2);     // dinv*(h1W2), stride 40

  dim3 b256(256);

  // bucket totals -> bases
  hipMemsetAsync(btot, 0, 512 * 4, stream);
  k_bcount<<<dim3((E + BCHUNK - 1) / BCHUNK), b256, 0, stream>>>(dst, btot, E, nbuck);
  k_bscan<<<dim3(1), dim3(512), 0, stream>>>(btot, bbase, bfill, nbuck, E);

  // partition + merged per-bucket CSR build (no global per-node atomics)
  k_partition<<<dim3((E + CHUNK - 1) / CHUNK), b256, 0, stream>>>(src, dst, bfill, tmp, E, nbuck);
  k_csr_build<<<dim3(nbuck), b256, 0, stream>>>(tmp, bbase, dinv, offset, ssrc, N, E, nbuck);

  // layer 1: g1 = dinv * (x @ W1);  h1 = relu(dinv*(g1[self]+sum g1[src]) + b1)
  k_gemm_mfma<128, 64, 4, 4, 64><<<dim3(256), b256, 0, stream>>>(x, W1, dinv, g1, N);
  k_agg_v8<64, 8, true><<<dim3((N + 3) / 4), b256, 0, stream>>>(
      (const uint4*)g1, offset, ssrc, dinv, b1, h1, N);

  // layer 2: g2 = dinv * (h1 @ W2); out = dinv*(g2[self]+sum g2[src]) + b2
  k_gemm_mfma<64, 40, 3, 2, 40><<<dim3(256), b256, 0, stream>>>(h1, W2, dinv, g2, N);
  k_agg_v8<40, 5, false><<<dim3((N + 3) / 4), b256, 0, stream>>>(
      (const uint4*)g2, offset, ssrc, dinv, b2, out, N);
}

// Round 11
// 264.760 us; speedup vs baseline: 1.8396x; 1.0188x over previous
//
#include <hip/hip_runtime.h>
#include <hip/hip_fp16.h>
#include <cstdint>
#include <cstddef>

#define NPB_SHIFT 8                      // 256 dst-nodes per bucket
#define NPB (1 << NPB_SHIFT)
#define CHUNK 4096                       // edges per partition block
#define BCHUNK 8192                      // edges per bucket-count block
// nbuck = ceil(N/256) must be <= 512 (N <= 131072) for the LDS arrays below.

typedef _Float16 half8_t __attribute__((ext_vector_type(8)));
typedef _Float16 half4_t __attribute__((ext_vector_type(4)));
typedef _Float16 half2_t __attribute__((ext_vector_type(2)));
typedef float floatx4 __attribute__((ext_vector_type(4)));

#define H2(u) __builtin_bit_cast(half2_t, (u))

// ---------------- graph preprocessing ----------------

// bucket histogram: LDS-aggregated, <=nbuck global atomics per block
__global__ __launch_bounds__(256) void k_bcount(const int* __restrict__ dst,
                                                int* __restrict__ btot, int E, int nbuck) {
  __shared__ int cnt[512];
  int tid = threadIdx.x;
  for (int i = tid; i < nbuck; i += 256) cnt[i] = 0;
  __syncthreads();
  int base = blockIdx.x * BCHUNK;
  int end = min(base + BCHUNK, E);
  for (int e = base + tid; e < end; e += 256) atomicAdd(&cnt[dst[e] >> NPB_SHIFT], 1);
  __syncthreads();
  for (int i = tid; i < nbuck; i += 256)
    if (cnt[i]) atomicAdd(&btot[i], cnt[i]);
}

// exclusive scan of bucket totals -> bucket bases (+ copy to bfill)
__global__ void k_bscan(const int* __restrict__ btot, int* __restrict__ bbase,
                        int* __restrict__ bfill, int nbuck, int E) {
  __shared__ int tmp[512];
  int tid = threadIdx.x;
  int v = (tid < nbuck) ? btot[tid] : 0;
  tmp[tid] = v;
  __syncthreads();
  for (int off = 1; off < 512; off <<= 1) {
    int t = (tid >= off) ? tmp[tid - off] : 0;
    __syncthreads();
    tmp[tid] += t;
    __syncthreads();
  }
  if (tid < nbuck) { int ex = tmp[tid] - v; bbase[tid] = ex; bfill[tid] = ex; }
  if (tid == 0) bbase[nbuck] = E;
}

// pass 1: LDS multisplit with in-LDS bucket sort; writes to tmp are
// LDS-order sequential -> coalesced runs per bucket segment.
__global__ __launch_bounds__(256) void k_partition(const int* __restrict__ src,
                                                   const int* __restrict__ dst,
                                                   int* __restrict__ bfill,
                                                   unsigned* __restrict__ tmp,
                                                   int E, int nbuck) {
  __shared__ int cnt[512];
  __shared__ int lbase[512];
  __shared__ int gdelta[512];
  __shared__ int cur[512];
  __shared__ int ps[256];
  __shared__ unsigned sval[CHUNK];
  __shared__ unsigned short sbid[CHUNK];
  int tid = threadIdx.x;
  int cbase = blockIdx.x * CHUNK;
  for (int i = tid; i < 512; i += 256) cnt[i] = 0;
  __syncthreads();
  int s[16], d[16];
  bool valid[16];
#pragma unroll
  for (int u = 0; u < 16; ++u) {
    int e = cbase + u * 256 + tid;
    valid[u] = e < E;
    s[u] = valid[u] ? src[e] : 0;
    d[u] = valid[u] ? dst[e] : 0;
    if (valid[u]) atomicAdd(&cnt[d[u] >> NPB_SHIFT], 1);
  }
  __syncthreads();
  // block-local exclusive scan of cnt[512] (2 entries per thread)
  int c0 = cnt[2 * tid], c1 = cnt[2 * tid + 1];
  int p = c0 + c1;
  ps[tid] = p;
  __syncthreads();
  for (int off = 1; off < 256; off <<= 1) {
    int t = (tid >= off) ? ps[tid - off] : 0;
    __syncthreads();
    ps[tid] += t;
    __syncthreads();
  }
  int ep = ps[tid] - p;                  // exclusive over pairs
  lbase[2 * tid] = ep;
  lbase[2 * tid + 1] = ep + c0;
  __syncthreads();
  for (int i = tid; i < 512; i += 256) {
    cur[i] = lbase[i];
    if (cnt[i]) gdelta[i] = atomicAdd(&bfill[i], cnt[i]) - lbase[i];
  }
  __syncthreads();
  // scatter into LDS in bucket-sorted order
#pragma unroll
  for (int u = 0; u < 16; ++u) {
    if (valid[u]) {
      int b = d[u] >> NPB_SHIFT;
      int r = atomicAdd(&cur[b], 1);
      sval[r] = ((unsigned)s[u] << NPB_SHIFT) | (unsigned)(d[u] & (NPB - 1));
      sbid[r] = (unsigned short)b;
    }
  }
  __syncthreads();
  // sequential LDS read -> coalesced global writes (runs per bucket)
  int nv = min(CHUNK, E - cbase);
  for (int i = tid; i < nv; i += 256) {
    unsigned v = sval[i];
    int b = sbid[i];
    tmp[gdelta[b] + i] = v;
  }
}

// per bucket (merged): LDS degree count -> dinv + offsets, then src-only CSR
// scatter. No remote-node data needed since norms are folded into the GEMMs.
__global__ __launch_bounds__(256) void k_csr_build(const unsigned* __restrict__ tmp,
                                                   const int* __restrict__ bbase,
                                                   float* __restrict__ dinv,
                                                   int* __restrict__ offset,
                                                   int* __restrict__ ssrc,
                                                   int N, int E, int nbuck) {
  __shared__ int cnt[NPB];
  __shared__ int scan[NPB];
  __shared__ int fillL[NPB];
  int b = blockIdx.x, tid = threadIdx.x;
  int nbase = b << NPB_SHIFT;
  int nloc = min(NPB, N - nbase);
  cnt[tid] = 0;
  __syncthreads();
  int ebeg = bbase[b], eend = bbase[b + 1];
  for (int j = ebeg + tid; j < eend; j += 256) atomicAdd(&cnt[tmp[j] & (NPB - 1)], 1);
  __syncthreads();
  int v = cnt[tid];
  scan[tid] = v;
  __syncthreads();
  for (int off = 1; off < NPB; off <<= 1) {
    int t = (tid >= off) ? scan[tid - off] : 0;
    __syncthreads();
    scan[tid] += t;
    __syncthreads();
  }
  int myoff = ebeg + scan[tid] - v;   // exclusive
  fillL[tid] = myoff;
  if (tid < nloc) {
    offset[nbase + tid] = myoff;
    dinv[nbase + tid] = rsqrtf((float)(v + 1));   // +1 self-loop
  }
  if (b == nbuck - 1 && tid == 0) offset[N] = E;
  __syncthreads();
  // scatter src indices into exact CSR slots (LDS fill counters, L2-local writes)
  int j = ebeg + tid;
  for (; j + 3 * 256 < eend; j += 4 * 256) {
    unsigned p[4];
#pragma unroll
    for (int u = 0; u < 4; ++u) p[u] = tmp[j + u * 256];
#pragma unroll
    for (int u = 0; u < 4; ++u) {
      int pos = atomicAdd(&fillL[p[u] & (NPB - 1)], 1);
      ssrc[pos] = (int)(p[u] >> NPB_SHIFT);
    }
  }
  for (; j < eend; j += 256) {
    unsigned p = tmp[j];
    int pos = atomicAdd(&fillL[p & (NPB - 1)], 1);
    ssrc[pos] = (int)(p >> NPB_SHIFT);
  }
}

// ---------------- dense layers: MFMA 16x16x32 f16, output scaled by dinv ------
// Writes g[node] = dinv[node] * (x @ W)[node] as fp16, row stride OS.
template <int K, int COLS, int MT, int KC, int OS>
__global__ __launch_bounds__(256) void k_gemm_mfma(const float* __restrict__ x,
                                                   const float* __restrict__ W,
                                                   const float* __restrict__ dinv,
                                                   _Float16* __restrict__ out, int n) {
  int lane = threadIdx.x & 63;
  int quad = lane >> 4;
  int l15 = lane & 15;
  int gwave = (blockIdx.x * blockDim.x + threadIdx.x) >> 6;
  int nwave = (gridDim.x * blockDim.x) >> 6;
  int ntiles = (n + 15) >> 4;

  half8_t afrag[MT][KC];
#pragma unroll
  for (int m = 0; m < MT; ++m) {
    int colw = m * 16 + l15;
    if (colw > COLS - 1) colw = COLS - 1;
#pragma unroll
    for (int c = 0; c < KC; ++c) {
#pragma unroll
      for (int j = 0; j < 8; ++j) {
        int kk = c * 32 + quad * 8 + j;
        afrag[m][c][j] = (_Float16)W[kk * COLS + colw];
      }
    }
  }

  for (int tile = gwave; tile < ntiles; tile += nwave) {
    int node0 = tile << 4;
    int nodeB = node0 + l15;
    int nodeC = nodeB < n ? nodeB : n - 1;
    const float* xr = x + (size_t)nodeC * K;
    float dv = dinv[nodeC];
    half8_t bfrag[KC];
#pragma unroll
    for (int c = 0; c < KC; ++c) {
      float4 lo = *(const float4*)(xr + c * 32 + quad * 8);
      float4 hi = *(const float4*)(xr + c * 32 + quad * 8 + 4);
      bfrag[c][0] = (_Float16)lo.x; bfrag[c][1] = (_Float16)lo.y;
      bfrag[c][2] = (_Float16)lo.z; bfrag[c][3] = (_Float16)lo.w;
      bfrag[c][4] = (_Float16)hi.x; bfrag[c][5] = (_Float16)hi.y;
      bfrag[c][6] = (_Float16)hi.z; bfrag[c][7] = (_Float16)hi.w;
    }
    floatx4 acc[MT];
#pragma unroll
    for (int m = 0; m < MT; ++m) acc[m] = (floatx4){0.f, 0.f, 0.f, 0.f};
#pragma unroll
    for (int c = 0; c < KC; ++c)
#pragma unroll
      for (int m = 0; m < MT; ++m)
        acc[m] = __builtin_amdgcn_mfma_f32_16x16x32_f16(afrag[m][c], bfrag[c], acc[m], 0, 0, 0);

    if (nodeB < n) {
#pragma unroll
      for (int m = 0; m < MT; ++m) {
        int colBase = m * 16 + quad * 4;
        if (colBase < COLS) {
          half4_t hv = {(_Float16)(acc[m][0] * dv), (_Float16)(acc[m][1] * dv),
                        (_Float16)(acc[m][2] * dv), (_Float16)(acc[m][3] * dv)};
          *(half4_t*)(out + (size_t)nodeB * OS + colBase) = hv;
        }
      }
    }
  }
}

// ---------------- aggregation: packed-fp16 accumulation ----------------
// Wave = 8 groups x 8 lanes; group g handles one edge, lane t loads uint4 =
// 8 fp16 feats (16B). Accumulate with v_pk_add_f16 (4 ops per row-slice);
// convert to fp32 once per node. out = dinv*(g[self]+sum g[src]) + bias.
template <int F, int S8, bool RELU>
__global__ __launch_bounds__(256) void k_agg_v8(const uint4* __restrict__ h8,
                                                const int* __restrict__ offset,
                                                const int* __restrict__ ssrc,
                                                const float* __restrict__ dinv,
                                                const float* __restrict__ bias,
                                                float* __restrict__ outp, int n) {
  constexpr int F8 = F / 8;            // used octets per row (8 or 5)
  int lane = threadIdx.x & 63;
  int g = lane >> 3;                   // edge group 0..7
  int t = lane & 7;                    // feature octet
  int node = (blockIdx.x * blockDim.x + threadIdx.x) >> 6;
  if (node >= n) return;
  bool tv = t < F8;
  float di = dinv[node];
  half2_t acc[4];
#pragma unroll
  for (int k = 0; k < 4; ++k) acc[k] = H2(0u);

  if (g == 0 && tv) {                  // self-loop term: g[node]
    uint4 v = h8[(size_t)node * S8 + t];
    acc[0] += H2(v.x); acc[1] += H2(v.y); acc[2] += H2(v.z); acc[3] += H2(v.w);
  }

  int beg = offset[node], end = offset[node + 1];
  int j = beg;
  for (; j + 16 <= end; j += 16) {
    int sA = ssrc[j + g];
    int sB = ssrc[j + 8 + g];
    uint4 rA = tv ? h8[(size_t)sA * S8 + t] : make_uint4(0, 0, 0, 0);
    uint4 rB = tv ? h8[(size_t)sB * S8 + t] : make_uint4(0, 0, 0, 0);
    acc[0] += H2(rA.x); acc[1] += H2(rA.y); acc[2] += H2(rA.z); acc[3] += H2(rA.w);
    acc[0] += H2(rB.x); acc[1] += H2(rB.y); acc[2] += H2(rB.z); acc[3] += H2(rB.w);
  }
  for (; j + 8 <= end; j += 8) {
    int s = ssrc[j + g];
    uint4 rv = tv ? h8[(size_t)s * S8 + t] : make_uint4(0, 0, 0, 0);
    acc[0] += H2(rv.x); acc[1] += H2(rv.y); acc[2] += H2(rv.z); acc[3] += H2(rv.w);
  }
  if (j < end) {                       // masked tail: 1..7 valid edges
    int r = end - j;
    int gi = (g < r) ? g : (r - 1);
    int s = ssrc[j + gi];
    uint4 rv = (tv && g < r) ? h8[(size_t)s * S8 + t] : make_uint4(0, 0, 0, 0);
    acc[0] += H2(rv.x); acc[1] += H2(rv.y); acc[2] += H2(rv.z); acc[3] += H2(rv.w);
  }

  // reduce across the 8 groups (packed shuffles)
#pragma unroll
  for (int k = 0; k < 4; ++k) {
    int u = __builtin_bit_cast(int, acc[k]);
    acc[k] += H2((unsigned)__shfl_xor(u, 8));
    u = __builtin_bit_cast(int, acc[k]);
    acc[k] += H2((unsigned)__shfl_xor(u, 16));
    u = __builtin_bit_cast(int, acc[k]);
    acc[k] += H2((unsigned)__shfl_xor(u, 32));
  }

  if (lane < F8) {
    float f[8];
#pragma unroll
    for (int k = 0; k < 4; ++k) {
      f[2 * k] = (float)acc[k][0];
      f[2 * k + 1] = (float)acc[k][1];
    }
    const float* bb = bias + lane * 8;
    float4 r0 = make_float4(fmaf(f[0], di, bb[0]), fmaf(f[1], di, bb[1]),
                            fmaf(f[2], di, bb[2]), fmaf(f[3], di, bb[3]));
    float4 r1 = make_float4(fmaf(f[4], di, bb[4]), fmaf(f[5], di, bb[5]),
                            fmaf(f[6], di, bb[6]), fmaf(f[7], di, bb[7]));
    if (RELU) {
      r0.x = fmaxf(r0.x, 0.f); r0.y = fmaxf(r0.y, 0.f);
      r0.z = fmaxf(r0.z, 0.f); r0.w = fmaxf(r0.w, 0.f);
      r1.x = fmaxf(r1.x, 0.f); r1.y = fmaxf(r1.y, 0.f);
      r1.z = fmaxf(r1.z, 0.f); r1.w = fmaxf(r1.w, 0.f);
    }
    float4* o4 = (float4*)(outp + (size_t)node * F + lane * 8);
    o4[0] = r0; o4[1] = r1;
  }
}

// ---------------- launch ----------------

extern "C" void kernel_launch(void* const* d_in, const int* in_sizes, int n_in,
                              void* d_out, int out_size, void* d_ws, size_t ws_size,
                              hipStream_t stream) {
  const float* x  = (const float*)d_in[0];
  const int*   ei = (const int*)d_in[1];
  const float* W1 = (const float*)d_in[2];
  const float* b1 = (const float*)d_in[3];
  const float* W2 = (const float*)d_in[4];
  const float* b2 = (const float*)d_in[5];
  float* out = (float*)d_out;

  const int F_IN = 128, HID = 64, C = 40;
  int N = in_sizes[0] / F_IN;
  int E = in_sizes[1] / 2;
  const int* src = ei;
  const int* dst = ei + E;
  int nbuck = (N + NPB - 1) >> NPB_SHIFT;   // 391 for N=100000

  char* w = (char*)d_ws;
  size_t o = 0;
  auto alloc = [&](size_t bytes) -> void* {
    void* p = w + o;
    o = (o + bytes + 255) & ~(size_t)255;
    return p;
  };
  float*    dinv   = (float*)alloc((size_t)N * 4);
  int*      offset = (int*)alloc((size_t)(N + 1) * 4);
  int*      btot   = (int*)alloc(512 * 4);
  int*      bbase  = (int*)alloc(513 * 4);
  int*      bfill  = (int*)alloc(512 * 4);
  unsigned* tmp    = (unsigned*)alloc((size_t)E * 4);
  int*      ssrc   = (int*)alloc((size_t)E * 4);
  _Float16* g1     = (_Float16*)alloc((size_t)N * HID * 2);   // dinv*(xW1), stride 64
  float*    h1     = (float*)alloc((size_t)N * HID * 4);      // fp32, streamed by gemm2
  _Float16* g2     = (_Float16*)alloc((size_t)N * C * 2);     // dinv*(h1W2), stride 40

  dim3 b256(256);

  // bucket totals -> bases
  hipMemsetAsync(btot, 0, 512 * 4, stream);
  k_bcount<<<dim3((E + BCHUNK - 1) / BCHUNK), b256, 0, stream>>>(dst, btot, E, nbuck);
  k_bscan<<<dim3(1), dim3(512), 0, stream>>>(btot, bbase, bfill, nbuck, E);

  // partition + merged per-bucket CSR build (no global per-node atomics)
  k_partition<<<dim3((E + CHUNK - 1) / CHUNK), b256, 0, stream>>>(src, dst, bfill, tmp, E, nbuck);
  k_csr_build<<<dim3(nbuck), b256, 0, stream>>>(tmp, bbase, dinv, offset, ssrc, N, E, nbuck);

  // layer 1: g1 = dinv * (x @ W1);  h1 = relu(dinv*(g1[self]+sum g1[src]) + b1)
  k_gemm_mfma<128, 64, 4, 4, 64><<<dim3(256), b256, 0, stream>>>(x, W1, dinv, g1, N);
  k_agg_v8<64, 8, true><<<dim3((N + 3) / 4), b256, 0, stream>>>(
      (const uint4*)g1, offset, ssrc, dinv, b1, h1, N);

  // layer 2: g2 = dinv * (h1 @ W2); out = dinv*(g2[self]+sum g2[src]) + b2
  k_gemm_mfma<64, 40, 3, 2, 40><<<dim3(256), b256, 0, stream>>>(h1, W2, dinv, g2, N);
  k_agg_v8<40, 5, false><<<dim3((N + 3) / 4), b256, 0, stream>>>(
      (const uint4*)g2, offset, ssrc, dinv, b2, out, N);
}